// Round 6
// baseline (511.467 us; speedup 1.0000x reference)
//
#include <hip/hip_runtime.h>
#include <math.h>

#define B_ 16
#define L_ 1024
#define H_ 8
#define U_ 35

typedef float f32x4 __attribute__((ext_vector_type(4)));
typedef short bf16x8 __attribute__((ext_vector_type(8)));

__device__ __forceinline__ unsigned short f2bf(float x) {
    unsigned int u = __float_as_uint(x);
    u += 0x7FFFu + ((u >> 16) & 1u);      // round-to-nearest-even
    return (unsigned short)(u >> 16);
}
__device__ __forceinline__ float bf2f(unsigned short b) {
    return __uint_as_float(((unsigned int)b) << 16);
}

// packed f32x2 -> bf16x2 in ONE VALU op (no builtin on gfx950; T12 recipe).
__device__ __forceinline__ unsigned int cvt_pk_bf16(float a, float b) {
    unsigned int r;
    asm("v_cvt_pk_bf16_f32 %0, %1, %2" : "=v"(r) : "v"(a), "v"(b));
    return r;
}

// async global->LDS, 16B per lane
__device__ __forceinline__ void gl_lds16(const void* g, void* l) {
    __builtin_amdgcn_global_load_lds(
        (const __attribute__((address_space(1))) unsigned int*)g,
        (__attribute__((address_space(3))) unsigned int*)l, 16, 0, 0);
}

#define MFMA(a, b, c) __builtin_amdgcn_mfma_f32_16x16x32_bf16((a), (b), (c), 0, 0, 0)

// ---------------- workspace layout (float-element offsets) ----------------
#define OFF_V      ((size_t)0)           // 8388608 f
#define OFF_QHI    ((size_t)8388608)     // 4194304
#define OFF_QLO    ((size_t)12582912)    // 4194304
#define OFF_CTXP   OFF_QHI               // ctx partials alias q_hi (dead after scores)
#define OFF_KHI    ((size_t)16777216)    // 4194304
#define OFF_KLO    ((size_t)20971520)    // 4194304
#define OFF_S      ((size_t)25165824)    // 4587520
#define OFF_WQH    OFF_S                 // W splits alias S (dead before scores)
#define OFF_WQL    ((size_t)(OFF_S + 131072))
#define OFF_WKH    ((size_t)(OFF_S + 262144))
#define OFF_WKL    ((size_t)(OFF_S + 393216))
#define OFF_WVH    ((size_t)(OFF_S + 524288))
#define OFF_WVL    ((size_t)(OFF_S + 655360))
#define OFF_M      ((size_t)29753344)    // 131072
#define OFF_KMEAN  ((size_t)29884416)    // 8192
#define OFF_VMEAN  ((size_t)29892608)    // 8192
#define OFF_CTXD   ((size_t)29900800)    // 286720 (ctx - vmean diffs)
#define OFF_IDX    ((size_t)30187520)    // 4480
#define OFF_OBASE  ((size_t)30192000)    // 8192 (per-b base output row)
// end ~30.2M f = ~121 MB

// ---------------------------------------------------------------
// split Wq/Wk/Wv fp32 -> hi/lo bf16; grid 3072 x 256
// ---------------------------------------------------------------
__global__ __launch_bounds__(256) void split_w3(
    const float* __restrict__ Wq, const float* __restrict__ Wk,
    const float* __restrict__ Wv,
    unsigned short* __restrict__ wqh, unsigned short* __restrict__ wql,
    unsigned short* __restrict__ wkh, unsigned short* __restrict__ wkl,
    unsigned short* __restrict__ wvh, unsigned short* __restrict__ wvl)
{
    const int w = blockIdx.x >> 10;
    const int i = (blockIdx.x & 1023) * 256 + threadIdx.x;
    const float* W = (w == 0) ? Wq : (w == 1) ? Wk : Wv;
    unsigned short* hi = (w == 0) ? wqh : (w == 1) ? wkh : wvh;
    unsigned short* lo = (w == 0) ? wql : (w == 1) ? wkl : wvl;
    float x = W[i];
    unsigned short h = f2bf(x);
    hi[i] = h;
    lo[i] = f2bf(x - bf2f(h));
}

// ---------------------------------------------------------------
// Fused bf16x2 MFMA GEMM for all three projections (z = q/k/v).
// R6 change: T14 reg-staging for B (issue-early / write-late).
// R5's B went via global_load_lds issued at the START of the stage
// phase -> barrier2's vmcnt(0) drain exposed ~200-800 cy of L2/HBM
// latency EVERY K-step (m97 finding: __syncthreads drains vmcnt).
// Now both A and B for tile k+1 are loaded into REGISTERS right after
// barrier2 (full MFMA phase to land) and written to LDS after
// barrier1 -> barrier2 waits only on lgkmcnt. LDS unchanged (36.9 KB,
// 4 blocks/CU); +16 VGPR. Values land identically -> absmax fixed.
// NOTE: SQ_LDS_BANK_CONFLICT (9437184) proven invariant to B-read
// swizzles (R2/R4/R5) — not a B-read artifact; do not chase it.
// ---------------------------------------------------------------
__global__ __launch_bounds__(256) void gemm_qkv(
    const float* __restrict__ Aq, const float* __restrict__ Ak,
    const float* __restrict__ Av,
    const unsigned short* __restrict__ wqh, const unsigned short* __restrict__ wql,
    const unsigned short* __restrict__ wkh, const unsigned short* __restrict__ wkl,
    const unsigned short* __restrict__ wvh, const unsigned short* __restrict__ wvl,
    const float* __restrict__ bqp, const float* __restrict__ bkp,
    const float* __restrict__ bvp,
    float* __restrict__ vout,
    unsigned short* __restrict__ qhi_o, unsigned short* __restrict__ qlo_o,
    unsigned short* __restrict__ khi_o, unsigned short* __restrict__ klo_o)
{
    // one raw LDS pool, aliased: staging (36864 B) then epilogue Cf (34816 B)
    __shared__ __align__(16) unsigned char smem[36864];
    unsigned short (*Ah)[40] = (unsigned short (*)[40])(smem);            // 10240 B
    unsigned short (*Al)[40] = (unsigned short (*)[40])(smem + 10240);    // 10240 B
    unsigned char* Bh = smem + 20480;                                     //  8192 B [128][32] rot
    unsigned char* Bl = smem + 28672;                                     //  8192 B
    float (*Cf)[68] = (float (*)[68])(smem);                              // 34816 B

    const int z = blockIdx.z;
    const float* A = (z == 0) ? Aq : (z == 1) ? Ak : Av;
    const unsigned short* Whi = (z == 0) ? wqh : (z == 1) ? wkh : wvh;
    const unsigned short* Wlo = (z == 0) ? wql : (z == 1) ? wkl : wvl;
    const float* bias = (z == 0) ? bqp : (z == 1) ? bkp : bvp;
    unsigned short* ohi = (z == 0) ? qhi_o : (z == 1) ? khi_o : nullptr;
    unsigned short* olo = (z == 0) ? qlo_o : (z == 1) ? klo_o : nullptr;

    const int tid = threadIdx.x, lane = tid & 63, wave = tid >> 6;
    const int m0 = blockIdx.x * 128, n0 = blockIdx.y * 128;
    const int wm = (wave >> 1) * 64, wn = (wave & 1) * 64;

    f32x4 zero4 = {0.f, 0.f, 0.f, 0.f};
    f32x4 acc[4][4];
#pragma unroll
    for (int i = 0; i < 4; i++)
#pragma unroll
        for (int j = 0; j < 4; j++) acc[i][j] = zero4;

    const int ar = tid >> 3, ac = (tid & 7) * 4;
    const int kc = (lane >> 4) * 8;
    const int q4 = lane >> 4;
    const int fr = lane & 15;
    // B staging: issue i covers rows i*64..+63 of the [128][32] tile.
    // Rotated source col (issue-independent since i*64 vanishes mod 4).
    const int btr = tid >> 2;                                    // row in issue
    const int btc = ((((tid & 3) - btr - (btr >> 2)) & 3)) * 8;  // rotated src col
    const int bldsoff = tid * 16;                                // linear dest

    // T14 prologue: tile-0 A AND B into registers
    float4 areg[4];
    uint4 bhr[2], blr[2];
#pragma unroll
    for (int p = 0; p < 4; ++p)
        areg[p] = *(const float4*)(A + (size_t)(m0 + ar + p * 32) * 512 + ac);
#pragma unroll
    for (int i = 0; i < 2; ++i) {
        size_t gb = (size_t)(n0 + i * 64 + btr) * 512 + btc;
        bhr[i] = *(const uint4*)(Whi + gb);
        blr[i] = *(const uint4*)(Wlo + gb);
    }

    for (int k0 = 0; k0 < 512; k0 += 32) {
        if (k0) __syncthreads();           // barrier1: prev readers done
        // --- B: reg -> LDS (linear b128 writes, conflict-free)
#pragma unroll
        for (int i = 0; i < 2; ++i) {
            *(uint4*)(Bh + i * 4096 + bldsoff) = bhr[i];
            *(uint4*)(Bl + i * 4096 + bldsoff) = blr[i];
        }
        // --- A: convert prefetched regs + ds_write
#pragma unroll
        for (int p = 0; p < 4; ++p) {
            float4 a4 = areg[p];
            unsigned int h01 = cvt_pk_bf16(a4.x, a4.y);
            unsigned int h23 = cvt_pk_bf16(a4.z, a4.w);
            float r0 = a4.x - __uint_as_float(h01 << 16);
            float r1 = a4.y - __uint_as_float(h01 & 0xFFFF0000u);
            float r2 = a4.z - __uint_as_float(h23 << 16);
            float r3 = a4.w - __uint_as_float(h23 & 0xFFFF0000u);
            unsigned int l01 = cvt_pk_bf16(r0, r1);
            unsigned int l23 = cvt_pk_bf16(r2, r3);
            uint2 hh; hh.x = h01; hh.y = h23;
            uint2 ll; ll.x = l01; ll.y = l23;
            *(uint2*)&Ah[ar + p * 32][ac] = hh;
            *(uint2*)&Al[ar + p * 32][ac] = ll;
        }
        __syncthreads();   // barrier2: only lgkmcnt outstanding -> cheap
        // T14: issue NEXT tile's A+B loads — fly under the MFMA phase.
        if (k0 + 32 < 512) {
#pragma unroll
            for (int p = 0; p < 4; ++p)
                areg[p] = *(const float4*)(A + (size_t)(m0 + ar + p * 32) * 512 + k0 + 32 + ac);
#pragma unroll
            for (int i = 0; i < 2; ++i) {
                size_t gb = (size_t)(n0 + i * 64 + btr) * 512 + k0 + 32 + btc;
                bhr[i] = *(const uint4*)(Whi + gb);
                blr[i] = *(const uint4*)(Wlo + gb);
            }
        }

        bf16x8 ah[4], al[4];
#pragma unroll
        for (int mi = 0; mi < 4; ++mi) {
            int row = wm + mi * 16 + fr;
            ah[mi] = *(bf16x8*)&Ah[row][kc];
            al[mi] = *(bf16x8*)&Al[row][kc];
        }
#pragma unroll
        for (int ni = 0; ni < 4; ++ni) {
            int rn = wn + ni * 16 + fr;
            int sl = (q4 + rn + (rn >> 2)) & 3;          // rotated read slot
            int bb = rn * 64 + sl * 16;
            bf16x8 bh8 = *(bf16x8*)(Bh + bb);
            bf16x8 bl8 = *(bf16x8*)(Bl + bb);
#pragma unroll
            for (int mi = 0; mi < 4; ++mi) {
                acc[mi][ni] = MFMA(ah[mi], bh8, acc[mi][ni]);
                acc[mi][ni] = MFMA(ah[mi], bl8, acc[mi][ni]);
                acc[mi][ni] = MFMA(al[mi], bh8, acc[mi][ni]);
            }
        }
    }

    // ---------------- epilogue: LDS-staged, coalesced stores ----------------
    const int col = lane & 15, rq = (lane >> 4) * 4;
    const int b_ = m0 >> 10;       // 128-row tile lies within one b
    const int l0 = m0 & 1023;

#pragma unroll
    for (int half = 0; half < 2; ++half) {
        __syncthreads();           // staging buffers dead / previous half stored
        if ((wave & 1) == half) {  // waves holding cols [half*64, half*64+64)
#pragma unroll
            for (int ni = 0; ni < 4; ++ni) {
                float bn = bias[n0 + half * 64 + ni * 16 + col];
#pragma unroll
                for (int mi = 0; mi < 4; ++mi)
#pragma unroll
                    for (int r = 0; r < 4; ++r)
                        Cf[wm + mi * 16 + rq + r][ni * 16 + col] = acc[mi][ni][r] + bn;
            }
        }
        __syncthreads();
        const int h_ = (n0 >> 6) + half;
        const size_t plane = ((size_t)(b_ * H_ + h_) * L_ + l0) * 64;
        if (z == 2) {
            const int r = tid >> 1, d0 = (tid & 1) * 32;
#pragma unroll
            for (int j = 0; j < 8; ++j) {
                float4 val = *(const float4*)&Cf[r][d0 + j * 4];
                *(float4*)(vout + plane + (size_t)r * 64 + d0 + j * 4) = val;
            }
        } else {
            const int r = tid >> 1, d0 = (tid & 1) * 32;
#pragma unroll
            for (int c = 0; c < 4; ++c) {
                float x[8];
#pragma unroll
                for (int j = 0; j < 8; ++j) x[j] = Cf[r][d0 + c * 8 + j];
                unsigned int h01 = cvt_pk_bf16(x[0], x[1]);
                unsigned int h23 = cvt_pk_bf16(x[2], x[3]);
                unsigned int h45 = cvt_pk_bf16(x[4], x[5]);
                unsigned int h67 = cvt_pk_bf16(x[6], x[7]);
                float r0 = x[0] - __uint_as_float(h01 << 16);
                float r1 = x[1] - __uint_as_float(h01 & 0xFFFF0000u);
                float r2 = x[2] - __uint_as_float(h23 << 16);
                float r3 = x[3] - __uint_as_float(h23 & 0xFFFF0000u);
                float r4 = x[4] - __uint_as_float(h45 << 16);
                float r5 = x[5] - __uint_as_float(h45 & 0xFFFF0000u);
                float r6 = x[6] - __uint_as_float(h67 << 16);
                float r7 = x[7] - __uint_as_float(h67 & 0xFFFF0000u);
                uint4 ph; ph.x = h01; ph.y = h23; ph.z = h45; ph.w = h67;
                uint4 pl;
                pl.x = cvt_pk_bf16(r0, r1);
                pl.y = cvt_pk_bf16(r2, r3);
                pl.z = cvt_pk_bf16(r4, r5);
                pl.w = cvt_pk_bf16(r6, r7);
                *(uint4*)(ohi + plane + (size_t)r * 64 + d0 + c * 8) = ph;
                *(uint4*)(olo + plane + (size_t)r * 64 + d0 + c * 8) = pl;
            }
        }
    }
}

// ---------------------------------------------------------------
// fused means: blocks 0..127 -> kmean (from k hi/lo), 128..255 -> vmean (fp32)
// ---------------------------------------------------------------
__global__ __launch_bounds__(256) void means_fused(
    const unsigned short* __restrict__ khi, const unsigned short* __restrict__ klo,
    const float* __restrict__ v, float* __restrict__ kmean, float* __restrict__ vmean)
{
    const int which = blockIdx.x >> 7;
    const int bh = blockIdx.x & 127;
    const int d = threadIdx.x & 63, g = threadIdx.x >> 6;
    __shared__ float red[4][64];
    float s = 0.f;
    if (which == 0) {
        size_t base = ((size_t)bh * L_ + g * 256) * 64 + d;
#pragma unroll 8
        for (int l = 0; l < 256; l++) {
            size_t o = base + (size_t)l * 64;
            s += bf2f(khi[o]) + bf2f(klo[o]);
        }
    } else {
        const float* p = v + ((size_t)bh * L_ + g * 256) * 64 + d;
#pragma unroll 8
        for (int l = 0; l < 256; l++) s += p[(size_t)l * 64];
    }
    red[g][d] = s;
    __syncthreads();
    if (threadIdx.x < 64) {
        const int dd = threadIdx.x;
        float m = (red[0][dd] + red[1][dd] + red[2][dd] + red[3][dd]) * (1.0f / 1024.0f);
        (which == 0 ? kmean : vmean)[(size_t)bh * 64 + dd] = m;
    }
}

// ---------------------------------------------------------------
// M[l] = max_k(q_l . k_k) - q_l . kmean via bf16x2 MFMA
// grid (128 bh, 16 qt) — R4 version (best measured): 64 q-rows/block,
// dbuf XOR-swizzled K via gload_lds, ONE barrier per K-tile.
// (R5's 128-row variant regressed: 72KB LDS -> 2 blocks/CU.)
// ---------------------------------------------------------------
__global__ __launch_bounds__(256) void qk_rowmax_mfma(
    const unsigned short* __restrict__ qhi, const unsigned short* __restrict__ qlo,
    const unsigned short* __restrict__ khi, const unsigned short* __restrict__ klo,
    const float* __restrict__ kmean, float* __restrict__ Mout)
{
    __shared__ unsigned short Qh[64][72], Ql[64][72];      // 18432 B
    __shared__ __align__(16) unsigned char Kp[2][2][8192]; // [buf][hi/lo], swz
    __shared__ float Mred[64][4];
    __shared__ float km[64];
    const int bh = blockIdx.x, q0 = blockIdx.y * 64;
    const int tid = threadIdx.x, lane = tid & 63, wave = tid >> 6;

    if (tid < 64) km[tid] = kmean[bh * 64 + tid];
    {
        int r = tid >> 2, c = (tid & 3) * 16;
        size_t off = ((size_t)bh * L_ + q0 + r) * 64 + c;
        *(uint4*)&Qh[r][c]     = *(const uint4*)(qhi + off);
        *(uint4*)&Qh[r][c + 8] = *(const uint4*)(qhi + off + 8);
        *(uint4*)&Ql[r][c]     = *(const uint4*)(qlo + off);
        *(uint4*)&Ql[r][c + 8] = *(const uint4*)(qlo + off + 8);
    }

    const size_t kb = (size_t)bh * L_ * 64;
    // K staging: 2 issues of 16B/lane cover 64 rows x 128B, XOR-swizzled
    // via per-lane source col (content slot = slot' ^ (row&7)).
    const int srow = tid >> 3;
    const int scol = ((tid & 7) ^ ((tid >> 3) & 7)) * 8;
    const int sdst = tid * 16;

    // stage K tile 0 into buf 0
    {
        size_t g0 = kb + (size_t)(srow) * 64 + scol;
        size_t g1 = kb + (size_t)(32 + srow) * 64 + scol;
        gl_lds16(khi + g0, &Kp[0][0][sdst]);
        gl_lds16(khi + g1, &Kp[0][0][4096 + sdst]);
        gl_lds16(klo + g0, &Kp[0][1][sdst]);
        gl_lds16(klo + g1, &Kp[0][1][4096 + sdst]);
    }
    __syncthreads();   // Q/km staged + K tile 0 complete (vmcnt+lgkm drain)

    const int fr = lane & 15;
    f32x4 zero4 = {0.f, 0.f, 0.f, 0.f};

    // hoist Q fragments into registers — invariant across the K loop
    bf16x8 qah[2][4], qal[2][4];
#pragma unroll
    for (int ks = 0; ks < 2; ++ks) {
        int kcol = ks * 32 + (lane >> 4) * 8;
#pragma unroll
        for (int mi = 0; mi < 4; ++mi) {
            qah[ks][mi] = *(bf16x8*)&Qh[mi * 16 + fr][kcol];
            qal[ks][mi] = *(bf16x8*)&Ql[mi * 16 + fr][kcol];
        }
    }

    float rmax[4][4];
#pragma unroll
    for (int mi = 0; mi < 4; ++mi)
#pragma unroll
        for (int r = 0; r < 4; ++r) rmax[mi][r] = -INFINITY;

    const int krow = wave * 16 + fr;
    const int kbase = krow * 128;
    const int kxor = (krow & 7) << 4;

    for (int kt = 0; kt < 16; ++kt) {
        const int cur = kt & 1;
        if (kt < 15) {   // stage next tile into the other buffer (async;
                         // in flight under the MFMAs, drained at the barrier)
            const int nb = cur ^ 1;
            size_t g0 = kb + (size_t)((kt + 1) * 64 + srow) * 64 + scol;
            size_t g1 = g0 + (size_t)32 * 64;
            gl_lds16(khi + g0, &Kp[nb][0][sdst]);
            gl_lds16(khi + g1, &Kp[nb][0][4096 + sdst]);
            gl_lds16(klo + g0, &Kp[nb][1][sdst]);
            gl_lds16(klo + g1, &Kp[nb][1][4096 + sdst]);
        }

        f32x4 acc[4];
#pragma unroll
        for (int mi = 0; mi < 4; ++mi) acc[mi] = zero4;

#pragma unroll
        for (int ks = 0; ks < 2; ++ks) {
            int byte = kbase + (((ks * 32 + (lane >> 4) * 8) * 2) ^ kxor);
            bf16x8 bh8 = *(bf16x8*)&Kp[cur][0][byte];
            bf16x8 bl8 = *(bf16x8*)&Kp[cur][1][byte];
#pragma unroll
            for (int mi = 0; mi < 4; ++mi) {
                acc[mi] = MFMA(qah[ks][mi], bh8, acc[mi]);
                acc[mi] = MFMA(qah[ks][mi], bl8, acc[mi]);
                acc[mi] = MFMA(qal[ks][mi], bh8, acc[mi]);
            }
        }
#pragma unroll
        for (int mi = 0; mi < 4; ++mi)
#pragma unroll
            for (int r = 0; r < 4; ++r)
                rmax[mi][r] = fmaxf(rmax[mi][r], acc[mi][r]);

        __syncthreads();   // next-tile loads drained; buffers synced
    }

    // reduce over the 16 k-columns held across lanes of each 16-group
#pragma unroll
    for (int mi = 0; mi < 4; ++mi)
#pragma unroll
        for (int r = 0; r < 4; ++r) {
            float v = rmax[mi][r];
            v = fmaxf(v, __shfl_xor(v, 1));
            v = fmaxf(v, __shfl_xor(v, 2));
            v = fmaxf(v, __shfl_xor(v, 4));
            v = fmaxf(v, __shfl_xor(v, 8));
            rmax[mi][r] = v;
        }
    if ((lane & 15) == 0) {
        int quad = lane >> 4;
#pragma unroll
        for (int mi = 0; mi < 4; ++mi)
#pragma unroll
            for (int r = 0; r < 4; ++r)
                Mred[mi * 16 + quad * 4 + r][wave] = rmax[mi][r];
    }
    __syncthreads();
    if (tid < 64) {
        float mx = fmaxf(fmaxf(Mred[tid][0], Mred[tid][1]),
                         fmaxf(Mred[tid][2], Mred[tid][3]));
        float dot = 0.f;
#pragma unroll 4
        for (int d = 0; d < 64; ++d)
            dot = fmaf(bf2f(Qh[tid][d]) + bf2f(Ql[tid][d]), km[d], dot);
        Mout[(size_t)bh * L_ + q0 + tid] = mx - dot;
    }
}

// ---------------------------------------------------------------
// top-35 of M[1024] per (b,h)
// ---------------------------------------------------------------
__global__ __launch_bounds__(256) void topk35(
    const float* __restrict__ Min, int* __restrict__ idx_out)
{
    const int bh = blockIdx.x;
    const int tid = threadIdx.x;
    __shared__ float vals[1024];
    __shared__ float wv[4];
    __shared__ int wi[4];
    for (int i = tid; i < 1024; i += 256) vals[i] = Min[(size_t)bh * 1024 + i];
    __syncthreads();
    for (int it = 0; it < U_; ++it) {
        float bv = -INFINITY; int bi = 1 << 30;
        for (int i = tid; i < 1024; i += 256) {
            float x = vals[i];
            if (x > bv) { bv = x; bi = i; }
        }
#pragma unroll
        for (int off = 32; off; off >>= 1) {
            float ov = __shfl_down(bv, off);
            int   oi = __shfl_down(bi, off);
            if (ov > bv || (ov == bv && oi < bi)) { bv = ov; bi = oi; }
        }
        if ((tid & 63) == 0) { wv[tid >> 6] = bv; wi[tid >> 6] = bi; }
        __syncthreads();
        if (tid == 0) {
#pragma unroll
            for (int w = 1; w < 4; ++w) {
                if (wv[w] > bv || (wv[w] == bv && wi[w] < bi)) { bv = wv[w]; bi = wi[w]; }
            }
            idx_out[bh * U_ + it] = bi;
            vals[bi] = -INFINITY;
        }
        __syncthreads();
    }
}

// ---------------------------------------------------------------
// S[u][k] = (q[idx_u] . k_k)/8 masked; grid (128 bh, 8 key-chunks)
// ---------------------------------------------------------------
__global__ __launch_bounds__(256) void scores_red(
    const unsigned short* __restrict__ qhi, const unsigned short* __restrict__ qlo,
    const unsigned short* __restrict__ khi, const unsigned short* __restrict__ klo,
    const int* __restrict__ idx, const int* __restrict__ mask,
    float* __restrict__ S)
{
    __shared__ float Qs[64][36];
    __shared__ float Ks[64][68];
    const int bh = blockIdx.x;
    const int b = bh >> 3;
    const int tid = threadIdx.x;
    const int tk = tid & 63, tg = tid >> 6;

    for (int t = tid; t < 36 * 64; t += 256) {
        int u = t >> 6, d = t & 63;
        float val = 0.f;
        if (u < U_) {
            int l = idx[bh * U_ + u];
            size_t off = ((size_t)bh * L_ + l) * 64 + d;
            val = bf2f(qhi[off]) + bf2f(qlo[off]);
        }
        Qs[d][u] = val;
    }

    const size_t kb = (size_t)bh * L_ * 64;
    const int sr = tid >> 2, sc = (tid & 3) * 16;
    float acc[9];
    const int kt0 = blockIdx.y * 2;
    for (int ki = 0; ki < 2; ++ki) {
        int kt = kt0 + ki;
        if (ki) __syncthreads();
        {
            size_t off = kb + (size_t)(kt * 64 + sr) * 64 + sc;
            uint4 h0 = *(const uint4*)(khi + off);
            uint4 h1 = *(const uint4*)(khi + off + 8);
            uint4 l0 = *(const uint4*)(klo + off);
            uint4 l1 = *(const uint4*)(klo + off + 8);
            unsigned short hv[16], lv[16];
            *(uint4*)hv = h0; *(uint4*)(hv + 8) = h1;
            *(uint4*)lv = l0; *(uint4*)(lv + 8) = l1;
#pragma unroll
            for (int i = 0; i < 16; ++i)
                Ks[sc + i][sr] = bf2f(hv[i]) + bf2f(lv[i]);
        }
        __syncthreads();
#pragma unroll
        for (int j = 0; j < 9; j++) acc[j] = 0.f;
#pragma unroll 4
        for (int d = 0; d < 64; ++d) {
            float kv = Ks[d][tk];
#pragma unroll
            for (int j = 0; j < 9; j++) acc[j] = fmaf(Qs[d][tg + 4 * j], kv, acc[j]);
        }
        const int kcol = kt * 64 + tk;
        const bool msk = (mask[b * L_ + kcol] == 0);
#pragma unroll
        for (int j = 0; j < 9; j++) {
            int u = tg + 4 * j;
            if (u < U_)
                S[((size_t)bh * U_ + u) * 1024 + kcol] = msk ? -INFINITY : acc[j] * 0.125f;
        }
    }
}

// ---------------------------------------------------------------
// softmax over 1024 per row; grid 4480 rows
// ---------------------------------------------------------------
__global__ __launch_bounds__(256) void softmax_rows(float* __restrict__ S)
{
    const size_t base = (size_t)blockIdx.x * 1024;
    const int tid = threadIdx.x;
    __shared__ float redm[4];
    __shared__ float reds[4];
    float4 v = *(const float4*)(S + base + tid * 4);
    float mx = fmaxf(fmaxf(v.x, v.y), fmaxf(v.z, v.w));
#pragma unroll
    for (int off = 32; off; off >>= 1) mx = fmaxf(mx, __shfl_down(mx, off));
    if ((tid & 63) == 0) redm[tid >> 6] = mx;
    __syncthreads();
    mx = fmaxf(fmaxf(redm[0], redm[1]), fmaxf(redm[2], redm[3]));
    float e0 = __expf(v.x - mx), e1 = __expf(v.y - mx);
    float e2 = __expf(v.z - mx), e3 = __expf(v.w - mx);
    float s = e0 + e1 + e2 + e3;
#pragma unroll
    for (int off = 32; off; off >>= 1) s += __shfl_down(s, off);
    if ((tid & 63) == 0) reds[tid >> 6] = s;
    __syncthreads();
    s = reds[0] + reds[1] + reds[2] + reds[3];
    const float inv = 1.0f / s;
    float4 o; o.x = e0 * inv; o.y = e1 * inv; o.z = e2 * inv; o.w = e3 * inv;
    *(float4*)(S + base + tid * 4) = o;
}

// ---------------------------------------------------------------
// ctx partials: grid (128 bh, 8 kc)
// ---------------------------------------------------------------
__global__ __launch_bounds__(256) void ctx_partial(
    const float* __restrict__ S, const float* __restrict__ v,
    float* __restrict__ ctxp)
{
    __shared__ float Vs[128][68];
    __shared__ float Wt[36][128];
    const int bh = blockIdx.x, kc = blockIdx.y;
    const int tid = threadIdx.x;
    const int td = tid & 63, tg = tid >> 6;
    const int lr = tid >> 2, lc0 = (tid & 3) * 16;

    const float* vbase = v + ((size_t)bh * L_ + kc * 128) * 64;
    const float* Sbase = S + (size_t)bh * U_ * 1024 + kc * 128;

#pragma unroll
    for (int hh = 0; hh < 2; ++hh) {
        int row = lr + hh * 64;
        const float* src = vbase + (size_t)row * 64 + lc0;
        *(float4*)&Vs[row][lc0 + 0]  = *(const float4*)(src + 0);
        *(float4*)&Vs[row][lc0 + 4]  = *(const float4*)(src + 4);
        *(float4*)&Vs[row][lc0 + 8]  = *(const float4*)(src + 8);
        *(float4*)&Vs[row][lc0 + 12] = *(const float4*)(src + 12);
    }
    for (int t = tid; t < 36 * 128; t += 256) {
        int u = t >> 7, kk = t & 127;
        Wt[u][kk] = (u < U_) ? Sbase[(size_t)u * 1024 + kk] : 0.f;
    }
    __syncthreads();

    float acc[9];
#pragma unroll
    for (int j = 0; j < 9; j++) acc[j] = 0.f;
#pragma unroll 2
    for (int kk = 0; kk < 128; ++kk) {
        float vv = Vs[kk][td];
#pragma unroll
        for (int j = 0; j < 9; j++) acc[j] = fmaf(Wt[tg + 4 * j][kk], vv, acc[j]);
    }
#pragma unroll
    for (int j = 0; j < 9; j++) {
        int u = tg + 4 * j;
        if (u < U_)
            ctxp[((size_t)(kc * 128 + bh) * 36 + u) * 64 + td] = acc[j];
    }
}

// ---------------------------------------------------------------
// ctxd[bh][u][d] = sum_kc ctxp - vmean[bh][d] ; grid 1120 x 256
// ---------------------------------------------------------------
__global__ __launch_bounds__(256) void ctx_reduce_diff(
    const float* __restrict__ ctxp, const float* __restrict__ vmean,
    float* __restrict__ ctxd)
{
    const int i = blockIdx.x * 256 + threadIdx.x;   // 128*35*64 = 286720
    const int d = i & 63;
    const int rest = i >> 6;
    const int u = rest % U_;
    const int bh = rest / U_;
    float s = 0.f;
#pragma unroll
    for (int kc = 0; kc < 8; ++kc)
        s += ctxp[((size_t)(kc * 128 + bh) * 36 + u) * 64 + d];
    ctxd[i] = s - vmean[(size_t)bh * 64 + d];
}

// ---------------------------------------------------------------
// obase[b][n] = dot(xbar[b], Wo[n]) + bo[n] ; grid 128 (16 b x 8 nchunk)
// ---------------------------------------------------------------
__global__ __launch_bounds__(256) void vmean_proj(
    const float* __restrict__ vmean, const float* __restrict__ Wo,
    const float* __restrict__ bo, float* __restrict__ obase)
{
    const int b = blockIdx.x >> 3, n0 = (blockIdx.x & 7) * 64;
    const int tid = threadIdx.x;
    __shared__ float xbar[512];
    __shared__ float psum[64][5];
    for (int i = tid; i < 512; i += 256)
        xbar[i] = vmean[(size_t)(b * 8 + (i >> 6)) * 64 + (i & 63)];
    __syncthreads();
    const int n = n0 + (tid >> 2), fq = (tid & 3) * 128;
    float s = 0.f;
    for (int f = 0; f < 128; f += 4) {
        float4 w = *(const float4*)(Wo + (size_t)n * 512 + fq + f);
        s += xbar[fq + f] * w.x + xbar[fq + f + 1] * w.y +
             xbar[fq + f + 2] * w.z + xbar[fq + f + 3] * w.w;
    }
    psum[tid >> 2][tid & 3] = s;
    __syncthreads();
    if (tid < 64)
        obase[(size_t)b * 512 + n0 + tid] =
            psum[tid][0] + psum[tid][1] + psum[tid][2] + psum[tid][3] + bo[n0 + tid];
}

// ---------------------------------------------------------------
// out[b][l][:] = obase[b][:] ; grid 8192 x 256 (float4)
// ---------------------------------------------------------------
__global__ void broadcast_out(const float* __restrict__ obase, float* __restrict__ out)
{
    const size_t e = ((size_t)blockIdx.x * 256 + threadIdx.x) * 4;
    const int n = (int)(e & 511);
    const int b = (int)(e >> 19);
    *(float4*)(out + e) = *(const float4*)(obase + (b << 9) + n);
}

// ---------------------------------------------------------------
// out[b][l_u][n] += ctxd[bh][u] . Wo[n][h*64..]
// grid (128 bh, 4 col-chunks) x 128 threads; one column n per thread.
// ---------------------------------------------------------------
__global__ __launch_bounds__(128) void delta_out(
    const float* __restrict__ ctxd, const int* __restrict__ idx,
    const float* __restrict__ Wo, float* __restrict__ out)
{
    const int bh = blockIdx.x, b = bh >> 3, h = bh & 7;
    const int tid = threadIdx.x;
    const int n = blockIdx.y * 128 + tid;
    __shared__ float sd[U_][64];
    __shared__ int ls[U_];
    if (tid < U_) ls[tid] = idx[bh * U_ + tid];
    for (int t = tid; t < U_ * 64; t += 128)
        sd[t >> 6][t & 63] = ctxd[(size_t)bh * U_ * 64 + t];

    float4 w[16];
    const float* wp = Wo + (size_t)n * 512 + h * 64;
#pragma unroll
    for (int jc = 0; jc < 16; ++jc) w[jc] = *(const float4*)(wp + jc * 4);
    __syncthreads();

    for (int u = 0; u < U_; ++u) {
        float acc = 0.f;
#pragma unroll
        for (int jc = 0; jc < 16; ++jc) {
            float4 dv = *(const float4*)&sd[u][jc * 4];
            acc = fmaf(dv.w, w[jc].w, fmaf(dv.z, w[jc].z,
                  fmaf(dv.y, w[jc].y, fmaf(dv.x, w[jc].x, acc))));
        }
        atomicAdd(out + ((size_t)b * L_ + ls[u]) * 512 + n, acc);
    }
}

// ---------------------------------------------------------------
extern "C" void kernel_launch(void* const* d_in, const int* in_sizes, int n_in,
                              void* d_out, int out_size, void* d_ws, size_t ws_size,
                              hipStream_t stream)
{
    (void)in_sizes; (void)n_in; (void)out_size; (void)ws_size;
    const float* query = (const float*)d_in[0];
    const float* key   = (const float*)d_in[1];
    const float* value = (const float*)d_in[2];
    const int*   mask  = (const int*)d_in[3];
    const float* Wq = (const float*)d_in[4];
    const float* bq = (const float*)d_in[5];
    const float* Wk = (const float*)d_in[6];
    const float* bk = (const float*)d_in[7];
    const float* Wv = (const float*)d_in[8];
    const float* bvp = (const float*)d_in[9];
    const float* Wo = (const float*)d_in[10];
    const float* bo = (const float*)d_in[11];
    float* out = (float*)d_out;

    float* ws = (float*)d_ws;
    float* v      = ws + OFF_V;
    unsigned short* q_hi = (unsigned short*)(ws + OFF_QHI);
    unsigned short* q_lo = (unsigned short*)(ws + OFF_QLO);
    unsigned short* k_hi = (unsigned short*)(ws + OFF_KHI);
    unsigned short* k_lo = (unsigned short*)(ws + OFF_KLO);
    float* ctxp   = ws + OFF_CTXP;
    float* S      = ws + OFF_S;
    float* Marr   = ws + OFF_M;
    float* kmean  = ws + OFF_KMEAN;
    float* vmean  = ws + OFF_VMEAN;
    float* ctxd   = ws + OFF_CTXD;
    int*   idx    = (int*)(ws + OFF_IDX);
    float* obase  = ws + OFF_OBASE;
    unsigned short* wqh = (unsigned short*)(ws + OFF_WQH);
    unsigned short* wql = (unsigned short*)(ws + OFF_WQL);
    unsigned short* wkh = (unsigned short*)(ws + OFF_WKH);
    unsigned short* wkl = (unsigned short*)(ws + OFF_WKL);
    unsigned short* wvh = (unsigned short*)(ws + OFF_WVH);
    unsigned short* wvl = (unsigned short*)(ws + OFF_WVL);

    // weight splits (fused)
    split_w3<<<3072, 256, 0, stream>>>(Wq, Wk, Wv, wqh, wql, wkh, wkl, wvh, wvl);

    // projections: fused dispatch, T14 reg-staging for BOTH A and B
    // (issue-early/write-late), rotated B slots, LDS-staged epilogue.
    gemm_qkv<<<dim3(128, 4, 3), 256, 0, stream>>>(
        query, key, value,
        wqh, wql, wkh, wkl, wvh, wvl,
        bq, bk, bvp,
        v, q_hi, q_lo, k_hi, k_lo);

    // per-(b,h) means (fused) + base output row
    means_fused<<<256, 256, 0, stream>>>(k_hi, k_lo, v, kmean, vmean);
    vmean_proj<<<128, 256, 0, stream>>>(vmean, Wo, bo, obase);

    // sparsity measure M (R4 config: 64 q-rows, dbuf gload_lds, 1 barrier/tile)
    qk_rowmax_mfma<<<dim3(128, 16), 256, 0, stream>>>(q_hi, q_lo, k_hi, k_lo, kmean, Marr);
    topk35<<<128, 256, 0, stream>>>(Marr, idx);

    // reduced attention (K-split for parallelism)
    scores_red<<<dim3(128, 8), 256, 0, stream>>>(q_hi, q_lo, k_hi, k_lo, idx, mask, S);
    softmax_rows<<<B_ * H_ * U_, 256, 0, stream>>>(S);
    ctx_partial<<<dim3(128, 8), 256, 0, stream>>>(S, v, ctxp);   // ctxp aliases q_hi (dead)
    ctx_reduce_diff<<<1120, 256, 0, stream>>>(ctxp, vmean, ctxd);

    // output = broadcast base row + sparse delta (replaces full Wo GEMM)
    broadcast_out<<<8192, 256, 0, stream>>>(obase, out);
    delta_out<<<dim3(128, 4), 128, 0, stream>>>(ctxd, idx, Wo, out);
}

// Round 7
// 490.019 us; speedup vs baseline: 1.0438x; 1.0438x over previous
//
#include <hip/hip_runtime.h>
#include <math.h>

#define B_ 16
#define L_ 1024
#define H_ 8
#define U_ 35

typedef float f32x4 __attribute__((ext_vector_type(4)));
typedef short bf16x8 __attribute__((ext_vector_type(8)));

__device__ __forceinline__ unsigned short f2bf(float x) {
    unsigned int u = __float_as_uint(x);
    u += 0x7FFFu + ((u >> 16) & 1u);      // round-to-nearest-even
    return (unsigned short)(u >> 16);
}
__device__ __forceinline__ float bf2f(unsigned short b) {
    return __uint_as_float(((unsigned int)b) << 16);
}

// packed f32x2 -> bf16x2 in ONE VALU op (no builtin on gfx950; T12 recipe).
__device__ __forceinline__ unsigned int cvt_pk_bf16(float a, float b) {
    unsigned int r;
    asm("v_cvt_pk_bf16_f32 %0, %1, %2" : "=v"(r) : "v"(a), "v"(b));
    return r;
}

// async global->LDS, 16B per lane
__device__ __forceinline__ void gl_lds16(const void* g, void* l) {
    __builtin_amdgcn_global_load_lds(
        (const __attribute__((address_space(1))) unsigned int*)g,
        (__attribute__((address_space(3))) unsigned int*)l, 16, 0, 0);
}

#define MFMA(a, b, c) __builtin_amdgcn_mfma_f32_16x16x32_bf16((a), (b), (c), 0, 0, 0)

// ---------------- workspace layout (float-element offsets) ----------------
#define OFF_V      ((size_t)0)           // 8388608 f
#define OFF_QHI    ((size_t)8388608)     // 4194304
#define OFF_QLO    ((size_t)12582912)    // 4194304
#define OFF_CTXP   OFF_QHI               // ctx partials alias q_hi (dead after scores)
#define OFF_KHI    ((size_t)16777216)    // 4194304
#define OFF_KLO    ((size_t)20971520)    // 4194304
#define OFF_S      ((size_t)25165824)    // 4587520
#define OFF_WQH    OFF_S                 // W splits alias S (dead before scores)
#define OFF_WQL    ((size_t)(OFF_S + 131072))
#define OFF_WKH    ((size_t)(OFF_S + 262144))
#define OFF_WKL    ((size_t)(OFF_S + 393216))
#define OFF_WVH    ((size_t)(OFF_S + 524288))
#define OFF_WVL    ((size_t)(OFF_S + 655360))
#define OFF_M      ((size_t)29753344)    // 131072
#define OFF_KMEAN  ((size_t)29884416)    // 8192
#define OFF_VMEAN  ((size_t)29892608)    // 8192
#define OFF_CTXD   ((size_t)29900800)    // 286720 (ctx - vmean diffs)
#define OFF_IDX    ((size_t)30187520)    // 4480
#define OFF_OBASE  ((size_t)30192000)    // 8192 (per-b base output row)
// end ~30.2M f = ~121 MB

// ---------------------------------------------------------------
// split Wq/Wk/Wv fp32 -> hi/lo bf16; grid 3072 x 256
// ---------------------------------------------------------------
__global__ __launch_bounds__(256) void split_w3(
    const float* __restrict__ Wq, const float* __restrict__ Wk,
    const float* __restrict__ Wv,
    unsigned short* __restrict__ wqh, unsigned short* __restrict__ wql,
    unsigned short* __restrict__ wkh, unsigned short* __restrict__ wkl,
    unsigned short* __restrict__ wvh, unsigned short* __restrict__ wvl)
{
    const int w = blockIdx.x >> 10;
    const int i = (blockIdx.x & 1023) * 256 + threadIdx.x;
    const float* W = (w == 0) ? Wq : (w == 1) ? Wk : Wv;
    unsigned short* hi = (w == 0) ? wqh : (w == 1) ? wkh : wvh;
    unsigned short* lo = (w == 0) ? wql : (w == 1) ? wkl : wvl;
    float x = W[i];
    unsigned short h = f2bf(x);
    hi[i] = h;
    lo[i] = f2bf(x - bf2f(h));
}

// ---------------------------------------------------------------
// Fused bf16x2 MFMA GEMM for all three projections (z = q/k/v).
// R7: REVERTED to the R5 version (best measured: 124.6 us).
// Lessons pinned here:
//  - B via global_load_lds (no VGPR roundtrip). R6's B reg-staging
//    SPILLED (+32 live VGPRs; compiler kept 96 cap): WRITE_SIZE
//    103->225 MB scratch, MfmaUtil 24.6->16.4, dur 124->195. Do not
//    reg-stage B here.
//  - A reg-prefetch (issue after barrier2, convert after barrier1)
//    is a win and fits the budget.
//  - SQ_LDS_BANK_CONFLICT = 9437184 is INVARIANT to B-read swizzles
//    (R2 linear / R4 XOR / R5 rotation) — not a B-read artifact;
//    do not chase it.
// ---------------------------------------------------------------
__global__ __launch_bounds__(256) void gemm_qkv(
    const float* __restrict__ Aq, const float* __restrict__ Ak,
    const float* __restrict__ Av,
    const unsigned short* __restrict__ wqh, const unsigned short* __restrict__ wql,
    const unsigned short* __restrict__ wkh, const unsigned short* __restrict__ wkl,
    const unsigned short* __restrict__ wvh, const unsigned short* __restrict__ wvl,
    const float* __restrict__ bqp, const float* __restrict__ bkp,
    const float* __restrict__ bvp,
    float* __restrict__ vout,
    unsigned short* __restrict__ qhi_o, unsigned short* __restrict__ qlo_o,
    unsigned short* __restrict__ khi_o, unsigned short* __restrict__ klo_o)
{
    // one raw LDS pool, aliased: staging (36864 B) then epilogue Cf (34816 B)
    __shared__ __align__(16) unsigned char smem[36864];
    unsigned short (*Ah)[40] = (unsigned short (*)[40])(smem);            // 10240 B
    unsigned short (*Al)[40] = (unsigned short (*)[40])(smem + 10240);    // 10240 B
    unsigned char* Bh = smem + 20480;                                     //  8192 B [128][32] rot
    unsigned char* Bl = smem + 28672;                                     //  8192 B
    float (*Cf)[68] = (float (*)[68])(smem);                              // 34816 B

    const int z = blockIdx.z;
    const float* A = (z == 0) ? Aq : (z == 1) ? Ak : Av;
    const unsigned short* Whi = (z == 0) ? wqh : (z == 1) ? wkh : wvh;
    const unsigned short* Wlo = (z == 0) ? wql : (z == 1) ? wkl : wvl;
    const float* bias = (z == 0) ? bqp : (z == 1) ? bkp : bvp;
    unsigned short* ohi = (z == 0) ? qhi_o : (z == 1) ? khi_o : nullptr;
    unsigned short* olo = (z == 0) ? qlo_o : (z == 1) ? klo_o : nullptr;

    const int tid = threadIdx.x, lane = tid & 63, wave = tid >> 6;
    const int m0 = blockIdx.x * 128, n0 = blockIdx.y * 128;
    const int wm = (wave >> 1) * 64, wn = (wave & 1) * 64;

    f32x4 zero4 = {0.f, 0.f, 0.f, 0.f};
    f32x4 acc[4][4];
#pragma unroll
    for (int i = 0; i < 4; i++)
#pragma unroll
        for (int j = 0; j < 4; j++) acc[i][j] = zero4;

    const int ar = tid >> 3, ac = (tid & 7) * 4;
    const int kc = (lane >> 4) * 8;
    const int q4 = lane >> 4;
    const int fr = lane & 15;
    // B staging: issue i covers rows i*64..+63 of the [128][32] tile.
    // Rotated source col (issue-independent since i*64 vanishes mod 4).
    const int btr = tid >> 2;                                    // row in issue
    const int btc = ((((tid & 3) - btr - (btr >> 2)) & 3)) * 8;  // rotated src col
    const int bldsoff = tid * 16;                                // linear dest

    // T14: prologue A loads (tile 0)
    float4 areg[4];
#pragma unroll
    for (int p = 0; p < 4; ++p)
        areg[p] = *(const float4*)(A + (size_t)(m0 + ar + p * 32) * 512 + ac);

    for (int k0 = 0; k0 < 512; k0 += 32) {
        if (k0) __syncthreads();           // barrier1: prev readers done
        // --- B: async global->LDS (rotated source, linear dest)
#pragma unroll
        for (int i = 0; i < 2; ++i) {
            size_t gb = (size_t)(n0 + i * 64 + btr) * 512 + k0 + btc;
            gl_lds16(Whi + gb, Bh + i * 4096 + bldsoff);
            gl_lds16(Wlo + gb, Bl + i * 4096 + bldsoff);
        }
        // --- A: convert prefetched regs (no fresh load latency here)
#pragma unroll
        for (int p = 0; p < 4; ++p) {
            float4 a4 = areg[p];
            unsigned int h01 = cvt_pk_bf16(a4.x, a4.y);
            unsigned int h23 = cvt_pk_bf16(a4.z, a4.w);
            float r0 = a4.x - __uint_as_float(h01 << 16);
            float r1 = a4.y - __uint_as_float(h01 & 0xFFFF0000u);
            float r2 = a4.z - __uint_as_float(h23 << 16);
            float r3 = a4.w - __uint_as_float(h23 & 0xFFFF0000u);
            unsigned int l01 = cvt_pk_bf16(r0, r1);
            unsigned int l23 = cvt_pk_bf16(r2, r3);
            uint2 hh; hh.x = h01; hh.y = h23;
            uint2 ll; ll.x = l01; ll.y = l23;
            *(uint2*)&Ah[ar + p * 32][ac] = hh;
            *(uint2*)&Al[ar + p * 32][ac] = ll;
        }
        __syncthreads();   // barrier2: drains B vmcnt + A ds_writes
        // T14: issue NEXT tile's A loads — fly under the MFMA phase,
        // consumed after the next barrier1.
        if (k0 + 32 < 512) {
#pragma unroll
            for (int p = 0; p < 4; ++p)
                areg[p] = *(const float4*)(A + (size_t)(m0 + ar + p * 32) * 512 + k0 + 32 + ac);
        }

        bf16x8 ah[4], al[4];
#pragma unroll
        for (int mi = 0; mi < 4; ++mi) {
            int row = wm + mi * 16 + fr;
            ah[mi] = *(bf16x8*)&Ah[row][kc];
            al[mi] = *(bf16x8*)&Al[row][kc];
        }
#pragma unroll
        for (int ni = 0; ni < 4; ++ni) {
            int rn = wn + ni * 16 + fr;
            int sl = (q4 + rn + (rn >> 2)) & 3;          // rotated read slot
            int bb = rn * 64 + sl * 16;
            bf16x8 bh8 = *(bf16x8*)(Bh + bb);
            bf16x8 bl8 = *(bf16x8*)(Bl + bb);
#pragma unroll
            for (int mi = 0; mi < 4; ++mi) {
                acc[mi][ni] = MFMA(ah[mi], bh8, acc[mi][ni]);
                acc[mi][ni] = MFMA(ah[mi], bl8, acc[mi][ni]);
                acc[mi][ni] = MFMA(al[mi], bh8, acc[mi][ni]);
            }
        }
    }

    // ---------------- epilogue: LDS-staged, coalesced stores ----------------
    const int col = lane & 15, rq = (lane >> 4) * 4;
    const int b_ = m0 >> 10;       // 128-row tile lies within one b
    const int l0 = m0 & 1023;

#pragma unroll
    for (int half = 0; half < 2; ++half) {
        __syncthreads();           // staging buffers dead / previous half stored
        if ((wave & 1) == half) {  // waves holding cols [half*64, half*64+64)
#pragma unroll
            for (int ni = 0; ni < 4; ++ni) {
                float bn = bias[n0 + half * 64 + ni * 16 + col];
#pragma unroll
                for (int mi = 0; mi < 4; ++mi)
#pragma unroll
                    for (int r = 0; r < 4; ++r)
                        Cf[wm + mi * 16 + rq + r][ni * 16 + col] = acc[mi][ni][r] + bn;
            }
        }
        __syncthreads();
        const int h_ = (n0 >> 6) + half;
        const size_t plane = ((size_t)(b_ * H_ + h_) * L_ + l0) * 64;
        if (z == 2) {
            const int r = tid >> 1, d0 = (tid & 1) * 32;
#pragma unroll
            for (int j = 0; j < 8; ++j) {
                float4 val = *(const float4*)&Cf[r][d0 + j * 4];
                *(float4*)(vout + plane + (size_t)r * 64 + d0 + j * 4) = val;
            }
        } else {
            const int r = tid >> 1, d0 = (tid & 1) * 32;
#pragma unroll
            for (int c = 0; c < 4; ++c) {
                float x[8];
#pragma unroll
                for (int j = 0; j < 8; ++j) x[j] = Cf[r][d0 + c * 8 + j];
                unsigned int h01 = cvt_pk_bf16(x[0], x[1]);
                unsigned int h23 = cvt_pk_bf16(x[2], x[3]);
                unsigned int h45 = cvt_pk_bf16(x[4], x[5]);
                unsigned int h67 = cvt_pk_bf16(x[6], x[7]);
                float r0 = x[0] - __uint_as_float(h01 << 16);
                float r1 = x[1] - __uint_as_float(h01 & 0xFFFF0000u);
                float r2 = x[2] - __uint_as_float(h23 << 16);
                float r3 = x[3] - __uint_as_float(h23 & 0xFFFF0000u);
                float r4 = x[4] - __uint_as_float(h45 << 16);
                float r5 = x[5] - __uint_as_float(h45 & 0xFFFF0000u);
                float r6 = x[6] - __uint_as_float(h67 << 16);
                float r7 = x[7] - __uint_as_float(h67 & 0xFFFF0000u);
                uint4 ph; ph.x = h01; ph.y = h23; ph.z = h45; ph.w = h67;
                uint4 pl;
                pl.x = cvt_pk_bf16(r0, r1);
                pl.y = cvt_pk_bf16(r2, r3);
                pl.z = cvt_pk_bf16(r4, r5);
                pl.w = cvt_pk_bf16(r6, r7);
                *(uint4*)(ohi + plane + (size_t)r * 64 + d0 + c * 8) = ph;
                *(uint4*)(olo + plane + (size_t)r * 64 + d0 + c * 8) = pl;
            }
        }
    }
}

// ---------------------------------------------------------------
// fused means: blocks 0..127 -> kmean (from k hi/lo), 128..255 -> vmean (fp32)
// ---------------------------------------------------------------
__global__ __launch_bounds__(256) void means_fused(
    const unsigned short* __restrict__ khi, const unsigned short* __restrict__ klo,
    const float* __restrict__ v, float* __restrict__ kmean, float* __restrict__ vmean)
{
    const int which = blockIdx.x >> 7;
    const int bh = blockIdx.x & 127;
    const int d = threadIdx.x & 63, g = threadIdx.x >> 6;
    __shared__ float red[4][64];
    float s = 0.f;
    if (which == 0) {
        size_t base = ((size_t)bh * L_ + g * 256) * 64 + d;
#pragma unroll 8
        for (int l = 0; l < 256; l++) {
            size_t o = base + (size_t)l * 64;
            s += bf2f(khi[o]) + bf2f(klo[o]);
        }
    } else {
        const float* p = v + ((size_t)bh * L_ + g * 256) * 64 + d;
#pragma unroll 8
        for (int l = 0; l < 256; l++) s += p[(size_t)l * 64];
    }
    red[g][d] = s;
    __syncthreads();
    if (threadIdx.x < 64) {
        const int dd = threadIdx.x;
        float m = (red[0][dd] + red[1][dd] + red[2][dd] + red[3][dd]) * (1.0f / 1024.0f);
        (which == 0 ? kmean : vmean)[(size_t)bh * 64 + dd] = m;
    }
}

// ---------------------------------------------------------------
// M[l] = max_k(q_l . k_k) - q_l . kmean via bf16x2 MFMA
// grid (128 bh, 16 qt) — R4 version (best measured): 64 q-rows/block,
// dbuf XOR-swizzled K via gload_lds, ONE barrier per K-tile.
// ---------------------------------------------------------------
__global__ __launch_bounds__(256) void qk_rowmax_mfma(
    const unsigned short* __restrict__ qhi, const unsigned short* __restrict__ qlo,
    const unsigned short* __restrict__ khi, const unsigned short* __restrict__ klo,
    const float* __restrict__ kmean, float* __restrict__ Mout)
{
    __shared__ unsigned short Qh[64][72], Ql[64][72];      // 18432 B
    __shared__ __align__(16) unsigned char Kp[2][2][8192]; // [buf][hi/lo], swz
    __shared__ float Mred[64][4];
    __shared__ float km[64];
    const int bh = blockIdx.x, q0 = blockIdx.y * 64;
    const int tid = threadIdx.x, lane = tid & 63, wave = tid >> 6;

    if (tid < 64) km[tid] = kmean[bh * 64 + tid];
    {
        int r = tid >> 2, c = (tid & 3) * 16;
        size_t off = ((size_t)bh * L_ + q0 + r) * 64 + c;
        *(uint4*)&Qh[r][c]     = *(const uint4*)(qhi + off);
        *(uint4*)&Qh[r][c + 8] = *(const uint4*)(qhi + off + 8);
        *(uint4*)&Ql[r][c]     = *(const uint4*)(qlo + off);
        *(uint4*)&Ql[r][c + 8] = *(const uint4*)(qlo + off + 8);
    }

    const size_t kb = (size_t)bh * L_ * 64;
    const int srow = tid >> 3;
    const int scol = ((tid & 7) ^ ((tid >> 3) & 7)) * 8;
    const int sdst = tid * 16;

    // stage K tile 0 into buf 0
    {
        size_t g0 = kb + (size_t)(srow) * 64 + scol;
        size_t g1 = kb + (size_t)(32 + srow) * 64 + scol;
        gl_lds16(khi + g0, &Kp[0][0][sdst]);
        gl_lds16(khi + g1, &Kp[0][0][4096 + sdst]);
        gl_lds16(klo + g0, &Kp[0][1][sdst]);
        gl_lds16(klo + g1, &Kp[0][1][4096 + sdst]);
    }
    __syncthreads();   // Q/km staged + K tile 0 complete (vmcnt+lgkm drain)

    const int fr = lane & 15;
    f32x4 zero4 = {0.f, 0.f, 0.f, 0.f};

    // hoist Q fragments into registers — invariant across the K loop
    bf16x8 qah[2][4], qal[2][4];
#pragma unroll
    for (int ks = 0; ks < 2; ++ks) {
        int kcol = ks * 32 + (lane >> 4) * 8;
#pragma unroll
        for (int mi = 0; mi < 4; ++mi) {
            qah[ks][mi] = *(bf16x8*)&Qh[mi * 16 + fr][kcol];
            qal[ks][mi] = *(bf16x8*)&Ql[mi * 16 + fr][kcol];
        }
    }

    float rmax[4][4];
#pragma unroll
    for (int mi = 0; mi < 4; ++mi)
#pragma unroll
        for (int r = 0; r < 4; ++r) rmax[mi][r] = -INFINITY;

    const int krow = wave * 16 + fr;
    const int kbase = krow * 128;
    const int kxor = (krow & 7) << 4;

    for (int kt = 0; kt < 16; ++kt) {
        const int cur = kt & 1;
        if (kt < 15) {   // stage next tile into the other buffer (async)
            const int nb = cur ^ 1;
            size_t g0 = kb + (size_t)((kt + 1) * 64 + srow) * 64 + scol;
            size_t g1 = g0 + (size_t)32 * 64;
            gl_lds16(khi + g0, &Kp[nb][0][sdst]);
            gl_lds16(khi + g1, &Kp[nb][0][4096 + sdst]);
            gl_lds16(klo + g0, &Kp[nb][1][sdst]);
            gl_lds16(klo + g1, &Kp[nb][1][4096 + sdst]);
        }

        f32x4 acc[4];
#pragma unroll
        for (int mi = 0; mi < 4; ++mi) acc[mi] = zero4;

#pragma unroll
        for (int ks = 0; ks < 2; ++ks) {
            int byte = kbase + (((ks * 32 + (lane >> 4) * 8) * 2) ^ kxor);
            bf16x8 bh8 = *(bf16x8*)&Kp[cur][0][byte];
            bf16x8 bl8 = *(bf16x8*)&Kp[cur][1][byte];
#pragma unroll
            for (int mi = 0; mi < 4; ++mi) {
                acc[mi] = MFMA(qah[ks][mi], bh8, acc[mi]);
                acc[mi] = MFMA(qah[ks][mi], bl8, acc[mi]);
                acc[mi] = MFMA(qal[ks][mi], bh8, acc[mi]);
            }
        }
#pragma unroll
        for (int mi = 0; mi < 4; ++mi)
#pragma unroll
            for (int r = 0; r < 4; ++r)
                rmax[mi][r] = fmaxf(rmax[mi][r], acc[mi][r]);

        __syncthreads();   // next-tile loads drained; buffers synced
    }

    // reduce over the 16 k-columns held across lanes of each 16-group
#pragma unroll
    for (int mi = 0; mi < 4; ++mi)
#pragma unroll
        for (int r = 0; r < 4; ++r) {
            float v = rmax[mi][r];
            v = fmaxf(v, __shfl_xor(v, 1));
            v = fmaxf(v, __shfl_xor(v, 2));
            v = fmaxf(v, __shfl_xor(v, 4));
            v = fmaxf(v, __shfl_xor(v, 8));
            rmax[mi][r] = v;
        }
    if ((lane & 15) == 0) {
        int quad = lane >> 4;
#pragma unroll
        for (int mi = 0; mi < 4; ++mi)
#pragma unroll
            for (int r = 0; r < 4; ++r)
                Mred[mi * 16 + quad * 4 + r][wave] = rmax[mi][r];
    }
    __syncthreads();
    if (tid < 64) {
        float mx = fmaxf(fmaxf(Mred[tid][0], Mred[tid][1]),
                         fmaxf(Mred[tid][2], Mred[tid][3]));
        float dot = 0.f;
#pragma unroll 4
        for (int d = 0; d < 64; ++d)
            dot = fmaf(bf2f(Qh[tid][d]) + bf2f(Ql[tid][d]), km[d], dot);
        Mout[(size_t)bh * L_ + q0 + tid] = mx - dot;
    }
}

// ---------------------------------------------------------------
// top-35 of M[1024] per (b,h) — radix-select rewrite (R7).
// Downstream use of idx is permutation-invariant (gather q by idx,
// scatter ctx by the same idx) -> only the SET matters. Find the
// exact 35th-largest key via 4x 8-bit radix passes on order-preserving
// uint32 keys, then compact: all strictly-greater (order-free) +
// smallest-index equals (matches jax top_k stable tie-break).
// 4 sweeps + 12 barriers vs 35 sweeps + 70 barriers before.
// ---------------------------------------------------------------
__global__ __launch_bounds__(256) void topk35(
    const float* __restrict__ Min, int* __restrict__ idx_out)
{
    const int bh = blockIdx.x;
    const int tid = threadIdx.x;
    __shared__ unsigned int keys[1024];
    __shared__ int hist[256];
    __shared__ unsigned int s_prefix;
    __shared__ int s_rank;
    __shared__ int s_cnt;

    for (int i = tid; i < 1024; i += 256) {
        unsigned int u = __float_as_uint(Min[(size_t)bh * 1024 + i]);
        // monotone map: larger float -> larger uint
        keys[i] = (u & 0x80000000u) ? ~u : (u | 0x80000000u);
    }
    if (tid == 0) { s_prefix = 0u; s_rank = U_; s_cnt = 0; }

    for (int p = 0; p < 4; ++p) {
        __syncthreads();               // keys/state ready; tid0 walk done
        hist[tid] = 0;                 // 256 threads zero 256 bins
        __syncthreads();
        const int sh = 24 - 8 * p;
        const unsigned int pref = s_prefix;
        for (int i = tid; i < 1024; i += 256) {
            unsigned int k = keys[i];
            bool m = (p == 0) || ((k >> (sh + 8)) == pref);
            if (m) atomicAdd(&hist[(k >> sh) & 255], 1);
        }
        __syncthreads();
        if (tid == 0) {
            int r = s_rank, cum = 0, b = 255;
            for (; b > 0; --b) { cum += hist[b]; if (cum >= r) break; }
            if (cum < r) cum += hist[0];   // b==0 fallthrough
            s_rank = r - (cum - hist[b]);
            s_prefix = (pref << 8) | (unsigned int)b;
        }
    }
    __syncthreads();
    const unsigned int T = s_prefix;   // key of the 35th-largest value
    // compact strictly-greater (exactly 35 - s_rank entries)
    for (int i = tid; i < 1024; i += 256) {
        if (keys[i] > T) {
            int pos = atomicAdd(&s_cnt, 1);
            idx_out[bh * U_ + pos] = i;
        }
    }
    __syncthreads();
    if (tid == 0) {                    // equals: smallest indices first
        int pos = s_cnt;
        for (int i = 0; i < 1024 && pos < U_; ++i)
            if (keys[i] == T) idx_out[bh * U_ + pos++] = i;
    }
}

// ---------------------------------------------------------------
// S[u][k] = (q[idx_u] . k_k)/8 masked; grid (128 bh, 8 key-chunks)
// ---------------------------------------------------------------
__global__ __launch_bounds__(256) void scores_red(
    const unsigned short* __restrict__ qhi, const unsigned short* __restrict__ qlo,
    const unsigned short* __restrict__ khi, const unsigned short* __restrict__ klo,
    const int* __restrict__ idx, const int* __restrict__ mask,
    float* __restrict__ S)
{
    __shared__ float Qs[64][36];
    __shared__ float Ks[64][68];
    const int bh = blockIdx.x;
    const int b = bh >> 3;
    const int tid = threadIdx.x;
    const int tk = tid & 63, tg = tid >> 6;

    for (int t = tid; t < 36 * 64; t += 256) {
        int u = t >> 6, d = t & 63;
        float val = 0.f;
        if (u < U_) {
            int l = idx[bh * U_ + u];
            size_t off = ((size_t)bh * L_ + l) * 64 + d;
            val = bf2f(qhi[off]) + bf2f(qlo[off]);
        }
        Qs[d][u] = val;
    }

    const size_t kb = (size_t)bh * L_ * 64;
    const int sr = tid >> 2, sc = (tid & 3) * 16;
    float acc[9];
    const int kt0 = blockIdx.y * 2;
    for (int ki = 0; ki < 2; ++ki) {
        int kt = kt0 + ki;
        if (ki) __syncthreads();
        {
            size_t off = kb + (size_t)(kt * 64 + sr) * 64 + sc;
            uint4 h0 = *(const uint4*)(khi + off);
            uint4 h1 = *(const uint4*)(khi + off + 8);
            uint4 l0 = *(const uint4*)(klo + off);
            uint4 l1 = *(const uint4*)(klo + off + 8);
            unsigned short hv[16], lv[16];
            *(uint4*)hv = h0; *(uint4*)(hv + 8) = h1;
            *(uint4*)lv = l0; *(uint4*)(lv + 8) = l1;
#pragma unroll
            for (int i = 0; i < 16; ++i)
                Ks[sc + i][sr] = bf2f(hv[i]) + bf2f(lv[i]);
        }
        __syncthreads();
#pragma unroll
        for (int j = 0; j < 9; j++) acc[j] = 0.f;
#pragma unroll 4
        for (int d = 0; d < 64; ++d) {
            float kv = Ks[d][tk];
#pragma unroll
            for (int j = 0; j < 9; j++) acc[j] = fmaf(Qs[d][tg + 4 * j], kv, acc[j]);
        }
        const int kcol = kt * 64 + tk;
        const bool msk = (mask[b * L_ + kcol] == 0);
#pragma unroll
        for (int j = 0; j < 9; j++) {
            int u = tg + 4 * j;
            if (u < U_)
                S[((size_t)bh * U_ + u) * 1024 + kcol] = msk ? -INFINITY : acc[j] * 0.125f;
        }
    }
}

// ---------------------------------------------------------------
// softmax over 1024 per row; grid 4480 rows
// ---------------------------------------------------------------
__global__ __launch_bounds__(256) void softmax_rows(float* __restrict__ S)
{
    const size_t base = (size_t)blockIdx.x * 1024;
    const int tid = threadIdx.x;
    __shared__ float redm[4];
    __shared__ float reds[4];
    float4 v = *(const float4*)(S + base + tid * 4);
    float mx = fmaxf(fmaxf(v.x, v.y), fmaxf(v.z, v.w));
#pragma unroll
    for (int off = 32; off; off >>= 1) mx = fmaxf(mx, __shfl_down(mx, off));
    if ((tid & 63) == 0) redm[tid >> 6] = mx;
    __syncthreads();
    mx = fmaxf(fmaxf(redm[0], redm[1]), fmaxf(redm[2], redm[3]));
    float e0 = __expf(v.x - mx), e1 = __expf(v.y - mx);
    float e2 = __expf(v.z - mx), e3 = __expf(v.w - mx);
    float s = e0 + e1 + e2 + e3;
#pragma unroll
    for (int off = 32; off; off >>= 1) s += __shfl_down(s, off);
    if ((tid & 63) == 0) reds[tid >> 6] = s;
    __syncthreads();
    s = reds[0] + reds[1] + reds[2] + reds[3];
    const float inv = 1.0f / s;
    float4 o; o.x = e0 * inv; o.y = e1 * inv; o.z = e2 * inv; o.w = e3 * inv;
    *(float4*)(S + base + tid * 4) = o;
}

// ---------------------------------------------------------------
// ctx partials: grid (128 bh, 8 kc)
// ---------------------------------------------------------------
__global__ __launch_bounds__(256) void ctx_partial(
    const float* __restrict__ S, const float* __restrict__ v,
    float* __restrict__ ctxp)
{
    __shared__ float Vs[128][68];
    __shared__ float Wt[36][128];
    const int bh = blockIdx.x, kc = blockIdx.y;
    const int tid = threadIdx.x;
    const int td = tid & 63, tg = tid >> 6;
    const int lr = tid >> 2, lc0 = (tid & 3) * 16;

    const float* vbase = v + ((size_t)bh * L_ + kc * 128) * 64;
    const float* Sbase = S + (size_t)bh * U_ * 1024 + kc * 128;

#pragma unroll
    for (int hh = 0; hh < 2; ++hh) {
        int row = lr + hh * 64;
        const float* src = vbase + (size_t)row * 64 + lc0;
        *(float4*)&Vs[row][lc0 + 0]  = *(const float4*)(src + 0);
        *(float4*)&Vs[row][lc0 + 4]  = *(const float4*)(src + 4);
        *(float4*)&Vs[row][lc0 + 8]  = *(const float4*)(src + 8);
        *(float4*)&Vs[row][lc0 + 12] = *(const float4*)(src + 12);
    }
    for (int t = tid; t < 36 * 128; t += 256) {
        int u = t >> 7, kk = t & 127;
        Wt[u][kk] = (u < U_) ? Sbase[(size_t)u * 1024 + kk] : 0.f;
    }
    __syncthreads();

    float acc[9];
#pragma unroll
    for (int j = 0; j < 9; j++) acc[j] = 0.f;
#pragma unroll 2
    for (int kk = 0; kk < 128; ++kk) {
        float vv = Vs[kk][td];
#pragma unroll
        for (int j = 0; j < 9; j++) acc[j] = fmaf(Wt[tg + 4 * j][kk], vv, acc[j]);
    }
#pragma unroll
    for (int j = 0; j < 9; j++) {
        int u = tg + 4 * j;
        if (u < U_)
            ctxp[((size_t)(kc * 128 + bh) * 36 + u) * 64 + td] = acc[j];
    }
}

// ---------------------------------------------------------------
// ctxd[bh][u][d] = sum_kc ctxp - vmean[bh][d] ; grid 1120 x 256
// ---------------------------------------------------------------
__global__ __launch_bounds__(256) void ctx_reduce_diff(
    const float* __restrict__ ctxp, const float* __restrict__ vmean,
    float* __restrict__ ctxd)
{
    const int i = blockIdx.x * 256 + threadIdx.x;   // 128*35*64 = 286720
    const int d = i & 63;
    const int rest = i >> 6;
    const int u = rest % U_;
    const int bh = rest / U_;
    float s = 0.f;
#pragma unroll
    for (int kc = 0; kc < 8; ++kc)
        s += ctxp[((size_t)(kc * 128 + bh) * 36 + u) * 64 + d];
    ctxd[i] = s - vmean[(size_t)bh * 64 + d];
}

// ---------------------------------------------------------------
// obase[b][n] = dot(xbar[b], Wo[n]) + bo[n] ; grid 128 (16 b x 8 nchunk)
// ---------------------------------------------------------------
__global__ __launch_bounds__(256) void vmean_proj(
    const float* __restrict__ vmean, const float* __restrict__ Wo,
    const float* __restrict__ bo, float* __restrict__ obase)
{
    const int b = blockIdx.x >> 3, n0 = (blockIdx.x & 7) * 64;
    const int tid = threadIdx.x;
    __shared__ float xbar[512];
    __shared__ float psum[64][5];
    for (int i = tid; i < 512; i += 256)
        xbar[i] = vmean[(size_t)(b * 8 + (i >> 6)) * 64 + (i & 63)];
    __syncthreads();
    const int n = n0 + (tid >> 2), fq = (tid & 3) * 128;
    float s = 0.f;
    for (int f = 0; f < 128; f += 4) {
        float4 w = *(const float4*)(Wo + (size_t)n * 512 + fq + f);
        s += xbar[fq + f] * w.x + xbar[fq + f + 1] * w.y +
             xbar[fq + f + 2] * w.z + xbar[fq + f + 3] * w.w;
    }
    psum[tid >> 2][tid & 3] = s;
    __syncthreads();
    if (tid < 64)
        obase[(size_t)b * 512 + n0 + tid] =
            psum[tid][0] + psum[tid][1] + psum[tid][2] + psum[tid][3] + bo[n0 + tid];
}

// ---------------------------------------------------------------
// out[b][l][:] = obase[b][:] ; grid 8192 x 256 (float4)
// ---------------------------------------------------------------
__global__ void broadcast_out(const float* __restrict__ obase, float* __restrict__ out)
{
    const size_t e = ((size_t)blockIdx.x * 256 + threadIdx.x) * 4;
    const int n = (int)(e & 511);
    const int b = (int)(e >> 19);
    *(float4*)(out + e) = *(const float4*)(obase + (b << 9) + n);
}

// ---------------------------------------------------------------
// out[b][l_u][n] += ctxd[bh][u] . Wo[n][h*64..]
// grid (128 bh, 4 col-chunks) x 128 threads; one column n per thread.
// ---------------------------------------------------------------
__global__ __launch_bounds__(128) void delta_out(
    const float* __restrict__ ctxd, const int* __restrict__ idx,
    const float* __restrict__ Wo, float* __restrict__ out)
{
    const int bh = blockIdx.x, b = bh >> 3, h = bh & 7;
    const int tid = threadIdx.x;
    const int n = blockIdx.y * 128 + tid;
    __shared__ float sd[U_][64];
    __shared__ int ls[U_];
    if (tid < U_) ls[tid] = idx[bh * U_ + tid];
    for (int t = tid; t < U_ * 64; t += 128)
        sd[t >> 6][t & 63] = ctxd[(size_t)bh * U_ * 64 + t];

    float4 w[16];
    const float* wp = Wo + (size_t)n * 512 + h * 64;
#pragma unroll
    for (int jc = 0; jc < 16; ++jc) w[jc] = *(const float4*)(wp + jc * 4);
    __syncthreads();

    for (int u = 0; u < U_; ++u) {
        float acc = 0.f;
#pragma unroll
        for (int jc = 0; jc < 16; ++jc) {
            float4 dv = *(const float4*)&sd[u][jc * 4];
            acc = fmaf(dv.w, w[jc].w, fmaf(dv.z, w[jc].z,
                  fmaf(dv.y, w[jc].y, fmaf(dv.x, w[jc].x, acc))));
        }
        atomicAdd(out + ((size_t)b * L_ + ls[u]) * 512 + n, acc);
    }
}

// ---------------------------------------------------------------
extern "C" void kernel_launch(void* const* d_in, const int* in_sizes, int n_in,
                              void* d_out, int out_size, void* d_ws, size_t ws_size,
                              hipStream_t stream)
{
    (void)in_sizes; (void)n_in; (void)out_size; (void)ws_size;
    const float* query = (const float*)d_in[0];
    const float* key   = (const float*)d_in[1];
    const float* value = (const float*)d_in[2];
    const int*   mask  = (const int*)d_in[3];
    const float* Wq = (const float*)d_in[4];
    const float* bq = (const float*)d_in[5];
    const float* Wk = (const float*)d_in[6];
    const float* bk = (const float*)d_in[7];
    const float* Wv = (const float*)d_in[8];
    const float* bvp = (const float*)d_in[9];
    const float* Wo = (const float*)d_in[10];
    const float* bo = (const float*)d_in[11];
    float* out = (float*)d_out;

    float* ws = (float*)d_ws;
    float* v      = ws + OFF_V;
    unsigned short* q_hi = (unsigned short*)(ws + OFF_QHI);
    unsigned short* q_lo = (unsigned short*)(ws + OFF_QLO);
    unsigned short* k_hi = (unsigned short*)(ws + OFF_KHI);
    unsigned short* k_lo = (unsigned short*)(ws + OFF_KLO);
    float* ctxp   = ws + OFF_CTXP;
    float* S      = ws + OFF_S;
    float* Marr   = ws + OFF_M;
    float* kmean  = ws + OFF_KMEAN;
    float* vmean  = ws + OFF_VMEAN;
    float* ctxd   = ws + OFF_CTXD;
    int*   idx    = (int*)(ws + OFF_IDX);
    float* obase  = ws + OFF_OBASE;
    unsigned short* wqh = (unsigned short*)(ws + OFF_WQH);
    unsigned short* wql = (unsigned short*)(ws + OFF_WQL);
    unsigned short* wkh = (unsigned short*)(ws + OFF_WKH);
    unsigned short* wkl = (unsigned short*)(ws + OFF_WKL);
    unsigned short* wvh = (unsigned short*)(ws + OFF_WVH);
    unsigned short* wvl = (unsigned short*)(ws + OFF_WVL);

    // weight splits (fused)
    split_w3<<<3072, 256, 0, stream>>>(Wq, Wk, Wv, wqh, wql, wkh, wkl, wvh, wvl);

    // projections: R5 config (gload_lds B + A reg-prefetch) — best measured.
    gemm_qkv<<<dim3(128, 4, 3), 256, 0, stream>>>(
        query, key, value,
        wqh, wql, wkh, wkl, wvh, wvl,
        bq, bk, bvp,
        v, q_hi, q_lo, k_hi, k_lo);

    // per-(b,h) means (fused) + base output row
    means_fused<<<256, 256, 0, stream>>>(k_hi, k_lo, v, kmean, vmean);
    vmean_proj<<<128, 256, 0, stream>>>(vmean, Wo, bo, obase);

    // sparsity measure M (R4 config: 64 q-rows, dbuf gload_lds, 1 barrier/tile)
    qk_rowmax_mfma<<<dim3(128, 16), 256, 0, stream>>>(q_hi, q_lo, k_hi, k_lo, kmean, Marr);
    topk35<<<128, 256, 0, stream>>>(Marr, idx);

    // reduced attention (K-split for parallelism)
    scores_red<<<dim3(128, 8), 256, 0, stream>>>(q_hi, q_lo, k_hi, k_lo, idx, mask, S);
    softmax_rows<<<B_ * H_ * U_, 256, 0, stream>>>(S);
    ctx_partial<<<dim3(128, 8), 256, 0, stream>>>(S, v, ctxp);   // ctxp aliases q_hi (dead)
    ctx_reduce_diff<<<1120, 256, 0, stream>>>(ctxp, vmean, ctxd);

    // output = broadcast base row + sparse delta (replaces full Wo GEMM)
    broadcast_out<<<8192, 256, 0, stream>>>(obase, out);
    delta_out<<<dim3(128, 4), 128, 0, stream>>>(ctxd, idx, Wo, out);
}

// Round 8
// 443.131 us; speedup vs baseline: 1.1542x; 1.1058x over previous
//
#include <hip/hip_runtime.h>
#include <math.h>

#define B_ 16
#define L_ 1024
#define H_ 8
#define U_ 35

typedef float f32x4 __attribute__((ext_vector_type(4)));
typedef short bf16x8 __attribute__((ext_vector_type(8)));

__device__ __forceinline__ unsigned short f2bf(float x) {
    unsigned int u = __float_as_uint(x);
    u += 0x7FFFu + ((u >> 16) & 1u);      // round-to-nearest-even
    return (unsigned short)(u >> 16);
}
__device__ __forceinline__ float bf2f(unsigned short b) {
    return __uint_as_float(((unsigned int)b) << 16);
}

// packed f32x2 -> bf16x2 in ONE VALU op (no builtin on gfx950; T12 recipe).
__device__ __forceinline__ unsigned int cvt_pk_bf16(float a, float b) {
    unsigned int r;
    asm("v_cvt_pk_bf16_f32 %0, %1, %2" : "=v"(r) : "v"(a), "v"(b));
    return r;
}

// async global->LDS, 16B per lane
__device__ __forceinline__ void gl_lds16(const void* g, void* l) {
    __builtin_amdgcn_global_load_lds(
        (const __attribute__((address_space(1))) unsigned int*)g,
        (__attribute__((address_space(3))) unsigned int*)l, 16, 0, 0);
}

#define MFMA(a, b, c) __builtin_amdgcn_mfma_f32_16x16x32_bf16((a), (b), (c), 0, 0, 0)

// ---------------- workspace layout (float-element offsets) ----------------
#define OFF_V      ((size_t)0)           // 8388608 f
#define OFF_QHI    ((size_t)8388608)     // 4194304
#define OFF_QLO    ((size_t)12582912)    // 4194304
#define OFF_CTXP   OFF_QHI               // ctx partials alias q_hi (dead after scores)
#define OFF_KHI    ((size_t)16777216)    // 4194304
#define OFF_KLO    ((size_t)20971520)    // 4194304
#define OFF_S      ((size_t)25165824)    // 4587520
#define OFF_WQH    OFF_S                 // W splits alias S (dead before scores)
#define OFF_WQL    ((size_t)(OFF_S + 131072))
#define OFF_WKH    ((size_t)(OFF_S + 262144))
#define OFF_WKL    ((size_t)(OFF_S + 393216))
#define OFF_WVH    ((size_t)(OFF_S + 524288))
#define OFF_WVL    ((size_t)(OFF_S + 655360))
#define OFF_M      ((size_t)29753344)    // 131072
#define OFF_KMEAN  ((size_t)29884416)    // 8192
#define OFF_VMEAN  ((size_t)29892608)    // 8192
#define OFF_CTXD   ((size_t)29900800)    // 286720 (ctx - vmean diffs)
#define OFF_IDX    ((size_t)30187520)    // 4480
#define OFF_OBASE  ((size_t)30192000)    // 8192 (per-b base output row)
// end ~30.2M f = ~121 MB

// ---------------------------------------------------------------
// split Wq/Wk/Wv fp32 -> hi/lo bf16; grid 3072 x 256
// ---------------------------------------------------------------
__global__ __launch_bounds__(256) void split_w3(
    const float* __restrict__ Wq, const float* __restrict__ Wk,
    const float* __restrict__ Wv,
    unsigned short* __restrict__ wqh, unsigned short* __restrict__ wql,
    unsigned short* __restrict__ wkh, unsigned short* __restrict__ wkl,
    unsigned short* __restrict__ wvh, unsigned short* __restrict__ wvl)
{
    const int w = blockIdx.x >> 10;
    const int i = (blockIdx.x & 1023) * 256 + threadIdx.x;
    const float* W = (w == 0) ? Wq : (w == 1) ? Wk : Wv;
    unsigned short* hi = (w == 0) ? wqh : (w == 1) ? wkh : wvh;
    unsigned short* lo = (w == 0) ? wql : (w == 1) ? wkl : wvl;
    float x = W[i];
    unsigned short h = f2bf(x);
    hi[i] = h;
    lo[i] = f2bf(x - bf2f(h));
}

// ---------------------------------------------------------------
// Fused bf16x2 MFMA GEMM for all three projections (z = q/k/v).
// R5 config — best measured (123 us). Pinned lessons:
//  - B via global_load_lds (no VGPR roundtrip). R6's B reg-staging
//    SPILLED (WRITE 103->225 MB scratch, dur 124->195). Don't.
//  - A reg-prefetch (issue after barrier2, convert after barrier1) is
//    a win and fits the 96-VGPR budget.
//  - SQ_LDS_BANK_CONFLICT = 9437184 is INVARIANT to B-read swizzles
//    (R2/R4/R5) — not a B-read artifact; do not chase it.
// ---------------------------------------------------------------
__global__ __launch_bounds__(256) void gemm_qkv(
    const float* __restrict__ Aq, const float* __restrict__ Ak,
    const float* __restrict__ Av,
    const unsigned short* __restrict__ wqh, const unsigned short* __restrict__ wql,
    const unsigned short* __restrict__ wkh, const unsigned short* __restrict__ wkl,
    const unsigned short* __restrict__ wvh, const unsigned short* __restrict__ wvl,
    const float* __restrict__ bqp, const float* __restrict__ bkp,
    const float* __restrict__ bvp,
    float* __restrict__ vout,
    unsigned short* __restrict__ qhi_o, unsigned short* __restrict__ qlo_o,
    unsigned short* __restrict__ khi_o, unsigned short* __restrict__ klo_o)
{
    // one raw LDS pool, aliased: staging (36864 B) then epilogue Cf (34816 B)
    __shared__ __align__(16) unsigned char smem[36864];
    unsigned short (*Ah)[40] = (unsigned short (*)[40])(smem);            // 10240 B
    unsigned short (*Al)[40] = (unsigned short (*)[40])(smem + 10240);    // 10240 B
    unsigned char* Bh = smem + 20480;                                     //  8192 B [128][32] rot
    unsigned char* Bl = smem + 28672;                                     //  8192 B
    float (*Cf)[68] = (float (*)[68])(smem);                              // 34816 B

    const int z = blockIdx.z;
    const float* A = (z == 0) ? Aq : (z == 1) ? Ak : Av;
    const unsigned short* Whi = (z == 0) ? wqh : (z == 1) ? wkh : wvh;
    const unsigned short* Wlo = (z == 0) ? wql : (z == 1) ? wkl : wvl;
    const float* bias = (z == 0) ? bqp : (z == 1) ? bkp : bvp;
    unsigned short* ohi = (z == 0) ? qhi_o : (z == 1) ? khi_o : nullptr;
    unsigned short* olo = (z == 0) ? qlo_o : (z == 1) ? klo_o : nullptr;

    const int tid = threadIdx.x, lane = tid & 63, wave = tid >> 6;
    const int m0 = blockIdx.x * 128, n0 = blockIdx.y * 128;
    const int wm = (wave >> 1) * 64, wn = (wave & 1) * 64;

    f32x4 zero4 = {0.f, 0.f, 0.f, 0.f};
    f32x4 acc[4][4];
#pragma unroll
    for (int i = 0; i < 4; i++)
#pragma unroll
        for (int j = 0; j < 4; j++) acc[i][j] = zero4;

    const int ar = tid >> 3, ac = (tid & 7) * 4;
    const int kc = (lane >> 4) * 8;
    const int q4 = lane >> 4;
    const int fr = lane & 15;
    const int btr = tid >> 2;                                    // row in issue
    const int btc = ((((tid & 3) - btr - (btr >> 2)) & 3)) * 8;  // rotated src col
    const int bldsoff = tid * 16;                                // linear dest

    // T14: prologue A loads (tile 0)
    float4 areg[4];
#pragma unroll
    for (int p = 0; p < 4; ++p)
        areg[p] = *(const float4*)(A + (size_t)(m0 + ar + p * 32) * 512 + ac);

    for (int k0 = 0; k0 < 512; k0 += 32) {
        if (k0) __syncthreads();           // barrier1: prev readers done
        // --- B: async global->LDS (rotated source, linear dest)
#pragma unroll
        for (int i = 0; i < 2; ++i) {
            size_t gb = (size_t)(n0 + i * 64 + btr) * 512 + k0 + btc;
            gl_lds16(Whi + gb, Bh + i * 4096 + bldsoff);
            gl_lds16(Wlo + gb, Bl + i * 4096 + bldsoff);
        }
        // --- A: convert prefetched regs (no fresh load latency here)
#pragma unroll
        for (int p = 0; p < 4; ++p) {
            float4 a4 = areg[p];
            unsigned int h01 = cvt_pk_bf16(a4.x, a4.y);
            unsigned int h23 = cvt_pk_bf16(a4.z, a4.w);
            float r0 = a4.x - __uint_as_float(h01 << 16);
            float r1 = a4.y - __uint_as_float(h01 & 0xFFFF0000u);
            float r2 = a4.z - __uint_as_float(h23 << 16);
            float r3 = a4.w - __uint_as_float(h23 & 0xFFFF0000u);
            unsigned int l01 = cvt_pk_bf16(r0, r1);
            unsigned int l23 = cvt_pk_bf16(r2, r3);
            uint2 hh; hh.x = h01; hh.y = h23;
            uint2 ll; ll.x = l01; ll.y = l23;
            *(uint2*)&Ah[ar + p * 32][ac] = hh;
            *(uint2*)&Al[ar + p * 32][ac] = ll;
        }
        __syncthreads();   // barrier2: drains B vmcnt + A ds_writes
        // T14: issue NEXT tile's A loads — fly under the MFMA phase.
        if (k0 + 32 < 512) {
#pragma unroll
            for (int p = 0; p < 4; ++p)
                areg[p] = *(const float4*)(A + (size_t)(m0 + ar + p * 32) * 512 + k0 + 32 + ac);
        }

        bf16x8 ah[4], al[4];
#pragma unroll
        for (int mi = 0; mi < 4; ++mi) {
            int row = wm + mi * 16 + fr;
            ah[mi] = *(bf16x8*)&Ah[row][kc];
            al[mi] = *(bf16x8*)&Al[row][kc];
        }
#pragma unroll
        for (int ni = 0; ni < 4; ++ni) {
            int rn = wn + ni * 16 + fr;
            int sl = (q4 + rn + (rn >> 2)) & 3;          // rotated read slot
            int bb = rn * 64 + sl * 16;
            bf16x8 bh8 = *(bf16x8*)(Bh + bb);
            bf16x8 bl8 = *(bf16x8*)(Bl + bb);
#pragma unroll
            for (int mi = 0; mi < 4; ++mi) {
                acc[mi][ni] = MFMA(ah[mi], bh8, acc[mi][ni]);
                acc[mi][ni] = MFMA(ah[mi], bl8, acc[mi][ni]);
                acc[mi][ni] = MFMA(al[mi], bh8, acc[mi][ni]);
            }
        }
    }

    // ---------------- epilogue: LDS-staged, coalesced stores ----------------
    const int col = lane & 15, rq = (lane >> 4) * 4;
    const int b_ = m0 >> 10;       // 128-row tile lies within one b
    const int l0 = m0 & 1023;

#pragma unroll
    for (int half = 0; half < 2; ++half) {
        __syncthreads();           // staging buffers dead / previous half stored
        if ((wave & 1) == half) {  // waves holding cols [half*64, half*64+64)
#pragma unroll
            for (int ni = 0; ni < 4; ++ni) {
                float bn = bias[n0 + half * 64 + ni * 16 + col];
#pragma unroll
                for (int mi = 0; mi < 4; ++mi)
#pragma unroll
                    for (int r = 0; r < 4; ++r)
                        Cf[wm + mi * 16 + rq + r][ni * 16 + col] = acc[mi][ni][r] + bn;
            }
        }
        __syncthreads();
        const int h_ = (n0 >> 6) + half;
        const size_t plane = ((size_t)(b_ * H_ + h_) * L_ + l0) * 64;
        if (z == 2) {
            const int r = tid >> 1, d0 = (tid & 1) * 32;
#pragma unroll
            for (int j = 0; j < 8; ++j) {
                float4 val = *(const float4*)&Cf[r][d0 + j * 4];
                *(float4*)(vout + plane + (size_t)r * 64 + d0 + j * 4) = val;
            }
        } else {
            const int r = tid >> 1, d0 = (tid & 1) * 32;
#pragma unroll
            for (int c = 0; c < 4; ++c) {
                float x[8];
#pragma unroll
                for (int j = 0; j < 8; ++j) x[j] = Cf[r][d0 + c * 8 + j];
                unsigned int h01 = cvt_pk_bf16(x[0], x[1]);
                unsigned int h23 = cvt_pk_bf16(x[2], x[3]);
                unsigned int h45 = cvt_pk_bf16(x[4], x[5]);
                unsigned int h67 = cvt_pk_bf16(x[6], x[7]);
                float r0 = x[0] - __uint_as_float(h01 << 16);
                float r1 = x[1] - __uint_as_float(h01 & 0xFFFF0000u);
                float r2 = x[2] - __uint_as_float(h23 << 16);
                float r3 = x[3] - __uint_as_float(h23 & 0xFFFF0000u);
                float r4 = x[4] - __uint_as_float(h45 << 16);
                float r5 = x[5] - __uint_as_float(h45 & 0xFFFF0000u);
                float r6 = x[6] - __uint_as_float(h67 << 16);
                float r7 = x[7] - __uint_as_float(h67 & 0xFFFF0000u);
                uint4 ph; ph.x = h01; ph.y = h23; ph.z = h45; ph.w = h67;
                uint4 pl;
                pl.x = cvt_pk_bf16(r0, r1);
                pl.y = cvt_pk_bf16(r2, r3);
                pl.z = cvt_pk_bf16(r4, r5);
                pl.w = cvt_pk_bf16(r6, r7);
                *(uint4*)(ohi + plane + (size_t)r * 64 + d0 + c * 8) = ph;
                *(uint4*)(olo + plane + (size_t)r * 64 + d0 + c * 8) = pl;
            }
        }
    }
}

// ---------------------------------------------------------------
// fused means: blocks 0..127 -> kmean (from k hi/lo), 128..255 -> vmean (fp32)
// ---------------------------------------------------------------
__global__ __launch_bounds__(256) void means_fused(
    const unsigned short* __restrict__ khi, const unsigned short* __restrict__ klo,
    const float* __restrict__ v, float* __restrict__ kmean, float* __restrict__ vmean)
{
    const int which = blockIdx.x >> 7;
    const int bh = blockIdx.x & 127;
    const int d = threadIdx.x & 63, g = threadIdx.x >> 6;
    __shared__ float red[4][64];
    float s = 0.f;
    if (which == 0) {
        size_t base = ((size_t)bh * L_ + g * 256) * 64 + d;
#pragma unroll 8
        for (int l = 0; l < 256; l++) {
            size_t o = base + (size_t)l * 64;
            s += bf2f(khi[o]) + bf2f(klo[o]);
        }
    } else {
        const float* p = v + ((size_t)bh * L_ + g * 256) * 64 + d;
#pragma unroll 8
        for (int l = 0; l < 256; l++) s += p[(size_t)l * 64];
    }
    red[g][d] = s;
    __syncthreads();
    if (threadIdx.x < 64) {
        const int dd = threadIdx.x;
        float m = (red[0][dd] + red[1][dd] + red[2][dd] + red[3][dd]) * (1.0f / 1024.0f);
        (which == 0 ? kmean : vmean)[(size_t)bh * 64 + dd] = m;
    }
}

// ---------------------------------------------------------------
// M[l] = max_k(q_l . k_k) - q_l . kmean via bf16x2 MFMA
// grid (128 bh, 16 qt). R8 change: Q staged into a TEMP ALIAS of
// Kp[0] (fragments hoisted + kmean-dot computed before the K loop
// needs Kp[0]) -> dedicated Q LDS (18.4 KB) eliminated.
// LDS 52.5 -> 33.25 KB: 3 -> 4 blocks/CU (R5 proved this kernel is
// occupancy-sensitive in the other direction). Fragment values, dot
// order, rmax math identical -> M bit-identical -> selection identical.
// ---------------------------------------------------------------
__global__ __launch_bounds__(256) void qk_rowmax_mfma(
    const unsigned short* __restrict__ qhi, const unsigned short* __restrict__ qlo,
    const unsigned short* __restrict__ khi, const unsigned short* __restrict__ klo,
    const float* __restrict__ kmean, float* __restrict__ Mout)
{
    __shared__ __align__(16) unsigned char Kp[2][2][8192]; // 32768 B dbuf swz
    __shared__ float Mred[64][4];                          //  1024 B
    __shared__ float km[64];                               //   256 B
    const int bh = blockIdx.x, q0 = blockIdx.y * 64;
    const int tid = threadIdx.x, lane = tid & 63, wave = tid >> 6;

    if (tid < 64) km[tid] = kmean[bh * 64 + tid];

    // ---- Phase 1: stage Q into Kp[0] alias ([64][64] shorts per hi/lo)
    unsigned short* Qt0 = (unsigned short*)&Kp[0][0][0];
    unsigned short* Qt1 = (unsigned short*)&Kp[0][1][0];
    {
        int r = tid >> 2, c = (tid & 3) * 16;
        size_t off = ((size_t)bh * L_ + q0 + r) * 64 + c;
        *(uint4*)&Qt0[r * 64 + c]     = *(const uint4*)(qhi + off);
        *(uint4*)&Qt0[r * 64 + c + 8] = *(const uint4*)(qhi + off + 8);
        *(uint4*)&Qt1[r * 64 + c]     = *(const uint4*)(qlo + off);
        *(uint4*)&Qt1[r * 64 + c + 8] = *(const uint4*)(qlo + off + 8);
    }
    __syncthreads();   // Q + km staged

    const int fr = lane & 15;
    f32x4 zero4 = {0.f, 0.f, 0.f, 0.f};

    // ---- Phase 2: hoist Q fragments + kmean dot (Qt dead afterwards)
    bf16x8 qah[2][4], qal[2][4];
#pragma unroll
    for (int ks = 0; ks < 2; ++ks) {
        int kcol = ks * 32 + (lane >> 4) * 8;
#pragma unroll
        for (int mi = 0; mi < 4; ++mi) {
            qah[ks][mi] = *(bf16x8*)&Qt0[(mi * 16 + fr) * 64 + kcol];
            qal[ks][mi] = *(bf16x8*)&Qt1[(mi * 16 + fr) * 64 + kcol];
        }
    }
    float ddot = 0.f;
    if (tid < 64) {
#pragma unroll 4
        for (int d = 0; d < 64; ++d)
            ddot = fmaf(bf2f(Qt0[tid * 64 + d]) + bf2f(Qt1[tid * 64 + d]), km[d], ddot);
    }
    __syncthreads();   // Qt alias dead -> Kp[0] free for K tile 0

    // ---- Phase 3: stage K tile 0 (XOR-swizzled via per-lane source col)
    const size_t kb = (size_t)bh * L_ * 64;
    const int srow = tid >> 3;
    const int scol = ((tid & 7) ^ ((tid >> 3) & 7)) * 8;
    const int sdst = tid * 16;
    {
        size_t g0 = kb + (size_t)(srow) * 64 + scol;
        size_t g1 = kb + (size_t)(32 + srow) * 64 + scol;
        gl_lds16(khi + g0, &Kp[0][0][sdst]);
        gl_lds16(khi + g1, &Kp[0][0][4096 + sdst]);
        gl_lds16(klo + g0, &Kp[0][1][sdst]);
        gl_lds16(klo + g1, &Kp[0][1][4096 + sdst]);
    }
    __syncthreads();   // K tile 0 complete (vmcnt drain)

    float rmax[4][4];
#pragma unroll
    for (int mi = 0; mi < 4; ++mi)
#pragma unroll
        for (int r = 0; r < 4; ++r) rmax[mi][r] = -INFINITY;

    const int krow = wave * 16 + fr;
    const int kbase = krow * 128;
    const int kxor = (krow & 7) << 4;

    for (int kt = 0; kt < 16; ++kt) {
        const int cur = kt & 1;
        if (kt < 15) {   // stage next tile into the other buffer (async)
            const int nb = cur ^ 1;
            size_t g0 = kb + (size_t)((kt + 1) * 64 + srow) * 64 + scol;
            size_t g1 = g0 + (size_t)32 * 64;
            gl_lds16(khi + g0, &Kp[nb][0][sdst]);
            gl_lds16(khi + g1, &Kp[nb][0][4096 + sdst]);
            gl_lds16(klo + g0, &Kp[nb][1][sdst]);
            gl_lds16(klo + g1, &Kp[nb][1][4096 + sdst]);
        }

        f32x4 acc[4];
#pragma unroll
        for (int mi = 0; mi < 4; ++mi) acc[mi] = zero4;

#pragma unroll
        for (int ks = 0; ks < 2; ++ks) {
            int byte = kbase + (((ks * 32 + (lane >> 4) * 8) * 2) ^ kxor);
            bf16x8 bh8 = *(bf16x8*)&Kp[cur][0][byte];
            bf16x8 bl8 = *(bf16x8*)&Kp[cur][1][byte];
#pragma unroll
            for (int mi = 0; mi < 4; ++mi) {
                acc[mi] = MFMA(qah[ks][mi], bh8, acc[mi]);
                acc[mi] = MFMA(qah[ks][mi], bl8, acc[mi]);
                acc[mi] = MFMA(qal[ks][mi], bh8, acc[mi]);
            }
        }
#pragma unroll
        for (int mi = 0; mi < 4; ++mi)
#pragma unroll
            for (int r = 0; r < 4; ++r)
                rmax[mi][r] = fmaxf(rmax[mi][r], acc[mi][r]);

        __syncthreads();   // next-tile loads drained; buffers synced
    }

    // reduce over the 16 k-columns held across lanes of each 16-group
#pragma unroll
    for (int mi = 0; mi < 4; ++mi)
#pragma unroll
        for (int r = 0; r < 4; ++r) {
            float v = rmax[mi][r];
            v = fmaxf(v, __shfl_xor(v, 1));
            v = fmaxf(v, __shfl_xor(v, 2));
            v = fmaxf(v, __shfl_xor(v, 4));
            v = fmaxf(v, __shfl_xor(v, 8));
            rmax[mi][r] = v;
        }
    if ((lane & 15) == 0) {
        int quad = lane >> 4;
#pragma unroll
        for (int mi = 0; mi < 4; ++mi)
#pragma unroll
            for (int r = 0; r < 4; ++r)
                Mred[mi * 16 + quad * 4 + r][wave] = rmax[mi][r];
    }
    __syncthreads();
    if (tid < 64) {
        float mx = fmaxf(fmaxf(Mred[tid][0], Mred[tid][1]),
                         fmaxf(Mred[tid][2], Mred[tid][3]));
        Mout[(size_t)bh * L_ + q0 + tid] = mx - ddot;
    }
}

// ---------------------------------------------------------------
// top-35 of M[1024] per (b,h) — iterative version (measured-good).
// R7's radix-select REGRESSED +62 us: clustered M values serialize
// the LDS atomic histogram, and the tid0 equals-scan is 1024 serial
// dependent LDS reads. Keep the dumb full-scan: 256 threads busy.
// ---------------------------------------------------------------
__global__ __launch_bounds__(256) void topk35(
    const float* __restrict__ Min, int* __restrict__ idx_out)
{
    const int bh = blockIdx.x;
    const int tid = threadIdx.x;
    __shared__ float vals[1024];
    __shared__ float wv[4];
    __shared__ int wi[4];
    for (int i = tid; i < 1024; i += 256) vals[i] = Min[(size_t)bh * 1024 + i];
    __syncthreads();
    for (int it = 0; it < U_; ++it) {
        float bv = -INFINITY; int bi = 1 << 30;
        for (int i = tid; i < 1024; i += 256) {
            float x = vals[i];
            if (x > bv) { bv = x; bi = i; }
        }
#pragma unroll
        for (int off = 32; off; off >>= 1) {
            float ov = __shfl_down(bv, off);
            int   oi = __shfl_down(bi, off);
            if (ov > bv || (ov == bv && oi < bi)) { bv = ov; bi = oi; }
        }
        if ((tid & 63) == 0) { wv[tid >> 6] = bv; wi[tid >> 6] = bi; }
        __syncthreads();
        if (tid == 0) {
#pragma unroll
            for (int w = 1; w < 4; ++w) {
                if (wv[w] > bv || (wv[w] == bv && wi[w] < bi)) { bv = wv[w]; bi = wi[w]; }
            }
            idx_out[bh * U_ + it] = bi;
            vals[bi] = -INFINITY;
        }
        __syncthreads();
    }
}

// ---------------------------------------------------------------
// S[u][k] = (q[idx_u] . k_k)/8 masked; grid (128 bh, 8 key-chunks)
// ---------------------------------------------------------------
__global__ __launch_bounds__(256) void scores_red(
    const unsigned short* __restrict__ qhi, const unsigned short* __restrict__ qlo,
    const unsigned short* __restrict__ khi, const unsigned short* __restrict__ klo,
    const int* __restrict__ idx, const int* __restrict__ mask,
    float* __restrict__ S)
{
    __shared__ float Qs[64][36];
    __shared__ float Ks[64][68];
    const int bh = blockIdx.x;
    const int b = bh >> 3;
    const int tid = threadIdx.x;
    const int tk = tid & 63, tg = tid >> 6;

    for (int t = tid; t < 36 * 64; t += 256) {
        int u = t >> 6, d = t & 63;
        float val = 0.f;
        if (u < U_) {
            int l = idx[bh * U_ + u];
            size_t off = ((size_t)bh * L_ + l) * 64 + d;
            val = bf2f(qhi[off]) + bf2f(qlo[off]);
        }
        Qs[d][u] = val;
    }

    const size_t kb = (size_t)bh * L_ * 64;
    const int sr = tid >> 2, sc = (tid & 3) * 16;
    float acc[9];
    const int kt0 = blockIdx.y * 2;
    for (int ki = 0; ki < 2; ++ki) {
        int kt = kt0 + ki;
        if (ki) __syncthreads();
        {
            size_t off = kb + (size_t)(kt * 64 + sr) * 64 + sc;
            uint4 h0 = *(const uint4*)(khi + off);
            uint4 h1 = *(const uint4*)(khi + off + 8);
            uint4 l0 = *(const uint4*)(klo + off);
            uint4 l1 = *(const uint4*)(klo + off + 8);
            unsigned short hv[16], lv[16];
            *(uint4*)hv = h0; *(uint4*)(hv + 8) = h1;
            *(uint4*)lv = l0; *(uint4*)(lv + 8) = l1;
#pragma unroll
            for (int i = 0; i < 16; ++i)
                Ks[sc + i][sr] = bf2f(hv[i]) + bf2f(lv[i]);
        }
        __syncthreads();
#pragma unroll
        for (int j = 0; j < 9; j++) acc[j] = 0.f;
#pragma unroll 4
        for (int d = 0; d < 64; ++d) {
            float kv = Ks[d][tk];
#pragma unroll
            for (int j = 0; j < 9; j++) acc[j] = fmaf(Qs[d][tg + 4 * j], kv, acc[j]);
        }
        const int kcol = kt * 64 + tk;
        const bool msk = (mask[b * L_ + kcol] == 0);
#pragma unroll
        for (int j = 0; j < 9; j++) {
            int u = tg + 4 * j;
            if (u < U_)
                S[((size_t)bh * U_ + u) * 1024 + kcol] = msk ? -INFINITY : acc[j] * 0.125f;
        }
    }
}

// ---------------------------------------------------------------
// softmax over 1024 per row; grid 4480 rows
// ---------------------------------------------------------------
__global__ __launch_bounds__(256) void softmax_rows(float* __restrict__ S)
{
    const size_t base = (size_t)blockIdx.x * 1024;
    const int tid = threadIdx.x;
    __shared__ float redm[4];
    __shared__ float reds[4];
    float4 v = *(const float4*)(S + base + tid * 4);
    float mx = fmaxf(fmaxf(v.x, v.y), fmaxf(v.z, v.w));
#pragma unroll
    for (int off = 32; off; off >>= 1) mx = fmaxf(mx, __shfl_down(mx, off));
    if ((tid & 63) == 0) redm[tid >> 6] = mx;
    __syncthreads();
    mx = fmaxf(fmaxf(redm[0], redm[1]), fmaxf(redm[2], redm[3]));
    float e0 = __expf(v.x - mx), e1 = __expf(v.y - mx);
    float e2 = __expf(v.z - mx), e3 = __expf(v.w - mx);
    float s = e0 + e1 + e2 + e3;
#pragma unroll
    for (int off = 32; off; off >>= 1) s += __shfl_down(s, off);
    if ((tid & 63) == 0) reds[tid >> 6] = s;
    __syncthreads();
    s = reds[0] + reds[1] + reds[2] + reds[3];
    const float inv = 1.0f / s;
    float4 o; o.x = e0 * inv; o.y = e1 * inv; o.z = e2 * inv; o.w = e3 * inv;
    *(float4*)(S + base + tid * 4) = o;
}

// ---------------------------------------------------------------
// ctx partials: grid (128 bh, 8 kc)
// ---------------------------------------------------------------
__global__ __launch_bounds__(256) void ctx_partial(
    const float* __restrict__ S, const float* __restrict__ v,
    float* __restrict__ ctxp)
{
    __shared__ float Vs[128][68];
    __shared__ float Wt[36][128];
    const int bh = blockIdx.x, kc = blockIdx.y;
    const int tid = threadIdx.x;
    const int td = tid & 63, tg = tid >> 6;
    const int lr = tid >> 2, lc0 = (tid & 3) * 16;

    const float* vbase = v + ((size_t)bh * L_ + kc * 128) * 64;
    const float* Sbase = S + (size_t)bh * U_ * 1024 + kc * 128;

#pragma unroll
    for (int hh = 0; hh < 2; ++hh) {
        int row = lr + hh * 64;
        const float* src = vbase + (size_t)row * 64 + lc0;
        *(float4*)&Vs[row][lc0 + 0]  = *(const float4*)(src + 0);
        *(float4*)&Vs[row][lc0 + 4]  = *(const float4*)(src + 4);
        *(float4*)&Vs[row][lc0 + 8]  = *(const float4*)(src + 8);
        *(float4*)&Vs[row][lc0 + 12] = *(const float4*)(src + 12);
    }
    for (int t = tid; t < 36 * 128; t += 256) {
        int u = t >> 7, kk = t & 127;
        Wt[u][kk] = (u < U_) ? Sbase[(size_t)u * 1024 + kk] : 0.f;
    }
    __syncthreads();

    float acc[9];
#pragma unroll
    for (int j = 0; j < 9; j++) acc[j] = 0.f;
#pragma unroll 2
    for (int kk = 0; kk < 128; ++kk) {
        float vv = Vs[kk][td];
#pragma unroll
        for (int j = 0; j < 9; j++) acc[j] = fmaf(Wt[tg + 4 * j][kk], vv, acc[j]);
    }
#pragma unroll
    for (int j = 0; j < 9; j++) {
        int u = tg + 4 * j;
        if (u < U_)
            ctxp[((size_t)(kc * 128 + bh) * 36 + u) * 64 + td] = acc[j];
    }
}

// ---------------------------------------------------------------
// ctxd[bh][u][d] = sum_kc ctxp - vmean[bh][d] ; grid 1120 x 256
// ---------------------------------------------------------------
__global__ __launch_bounds__(256) void ctx_reduce_diff(
    const float* __restrict__ ctxp, const float* __restrict__ vmean,
    float* __restrict__ ctxd)
{
    const int i = blockIdx.x * 256 + threadIdx.x;   // 128*35*64 = 286720
    const int d = i & 63;
    const int rest = i >> 6;
    const int u = rest % U_;
    const int bh = rest / U_;
    float s = 0.f;
#pragma unroll
    for (int kc = 0; kc < 8; ++kc)
        s += ctxp[((size_t)(kc * 128 + bh) * 36 + u) * 64 + d];
    ctxd[i] = s - vmean[(size_t)bh * 64 + d];
}

// ---------------------------------------------------------------
// obase[b][n] = dot(xbar[b], Wo[n]) + bo[n] ; grid 128 (16 b x 8 nchunk)
// ---------------------------------------------------------------
__global__ __launch_bounds__(256) void vmean_proj(
    const float* __restrict__ vmean, const float* __restrict__ Wo,
    const float* __restrict__ bo, float* __restrict__ obase)
{
    const int b = blockIdx.x >> 3, n0 = (blockIdx.x & 7) * 64;
    const int tid = threadIdx.x;
    __shared__ float xbar[512];
    __shared__ float psum[64][5];
    for (int i = tid; i < 512; i += 256)
        xbar[i] = vmean[(size_t)(b * 8 + (i >> 6)) * 64 + (i & 63)];
    __syncthreads();
    const int n = n0 + (tid >> 2), fq = (tid & 3) * 128;
    float s = 0.f;
    for (int f = 0; f < 128; f += 4) {
        float4 w = *(const float4*)(Wo + (size_t)n * 512 + fq + f);
        s += xbar[fq + f] * w.x + xbar[fq + f + 1] * w.y +
             xbar[fq + f + 2] * w.z + xbar[fq + f + 3] * w.w;
    }
    psum[tid >> 2][tid & 3] = s;
    __syncthreads();
    if (tid < 64)
        obase[(size_t)b * 512 + n0 + tid] =
            psum[tid][0] + psum[tid][1] + psum[tid][2] + psum[tid][3] + bo[n0 + tid];
}

// ---------------------------------------------------------------
// out[b][l][:] = obase[b][:] ; grid 8192 x 256 (float4)
// ---------------------------------------------------------------
__global__ void broadcast_out(const float* __restrict__ obase, float* __restrict__ out)
{
    const size_t e = ((size_t)blockIdx.x * 256 + threadIdx.x) * 4;
    const int n = (int)(e & 511);
    const int b = (int)(e >> 19);
    *(float4*)(out + e) = *(const float4*)(obase + (b << 9) + n);
}

// ---------------------------------------------------------------
// out[b][l_u][n] += ctxd[bh][u] . Wo[n][h*64..]
// grid (128 bh, 4 col-chunks) x 128 threads; one column n per thread.
// ---------------------------------------------------------------
__global__ __launch_bounds__(128) void delta_out(
    const float* __restrict__ ctxd, const int* __restrict__ idx,
    const float* __restrict__ Wo, float* __restrict__ out)
{
    const int bh = blockIdx.x, b = bh >> 3, h = bh & 7;
    const int tid = threadIdx.x;
    const int n = blockIdx.y * 128 + tid;
    __shared__ float sd[U_][64];
    __shared__ int ls[U_];
    if (tid < U_) ls[tid] = idx[bh * U_ + tid];
    for (int t = tid; t < U_ * 64; t += 128)
        sd[t >> 6][t & 63] = ctxd[(size_t)bh * U_ * 64 + t];

    float4 w[16];
    const float* wp = Wo + (size_t)n * 512 + h * 64;
#pragma unroll
    for (int jc = 0; jc < 16; ++jc) w[jc] = *(const float4*)(wp + jc * 4);
    __syncthreads();

    for (int u = 0; u < U_; ++u) {
        float acc = 0.f;
#pragma unroll
        for (int jc = 0; jc < 16; ++jc) {
            float4 dv = *(const float4*)&sd[u][jc * 4];
            acc = fmaf(dv.w, w[jc].w, fmaf(dv.z, w[jc].z,
                  fmaf(dv.y, w[jc].y, fmaf(dv.x, w[jc].x, acc))));
        }
        atomicAdd(out + ((size_t)b * L_ + ls[u]) * 512 + n, acc);
    }
}

// ---------------------------------------------------------------
extern "C" void kernel_launch(void* const* d_in, const int* in_sizes, int n_in,
                              void* d_out, int out_size, void* d_ws, size_t ws_size,
                              hipStream_t stream)
{
    (void)in_sizes; (void)n_in; (void)out_size; (void)ws_size;
    const float* query = (const float*)d_in[0];
    const float* key   = (const float*)d_in[1];
    const float* value = (const float*)d_in[2];
    const int*   mask  = (const int*)d_in[3];
    const float* Wq = (const float*)d_in[4];
    const float* bq = (const float*)d_in[5];
    const float* Wk = (const float*)d_in[6];
    const float* bk = (const float*)d_in[7];
    const float* Wv = (const float*)d_in[8];
    const float* bvp = (const float*)d_in[9];
    const float* Wo = (const float*)d_in[10];
    const float* bo = (const float*)d_in[11];
    float* out = (float*)d_out;

    float* ws = (float*)d_ws;
    float* v      = ws + OFF_V;
    unsigned short* q_hi = (unsigned short*)(ws + OFF_QHI);
    unsigned short* q_lo = (unsigned short*)(ws + OFF_QLO);
    unsigned short* k_hi = (unsigned short*)(ws + OFF_KHI);
    unsigned short* k_lo = (unsigned short*)(ws + OFF_KLO);
    float* ctxp   = ws + OFF_CTXP;
    float* S      = ws + OFF_S;
    float* Marr   = ws + OFF_M;
    float* kmean  = ws + OFF_KMEAN;
    float* vmean  = ws + OFF_VMEAN;
    float* ctxd   = ws + OFF_CTXD;
    int*   idx    = (int*)(ws + OFF_IDX);
    float* obase  = ws + OFF_OBASE;
    unsigned short* wqh = (unsigned short*)(ws + OFF_WQH);
    unsigned short* wql = (unsigned short*)(ws + OFF_WQL);
    unsigned short* wkh = (unsigned short*)(ws + OFF_WKH);
    unsigned short* wkl = (unsigned short*)(ws + OFF_WKL);
    unsigned short* wvh = (unsigned short*)(ws + OFF_WVH);
    unsigned short* wvl = (unsigned short*)(ws + OFF_WVL);

    // weight splits (fused)
    split_w3<<<3072, 256, 0, stream>>>(Wq, Wk, Wv, wqh, wql, wkh, wkl, wvh, wvl);

    // projections: R5 config (gload_lds B + A reg-prefetch) — best measured.
    gemm_qkv<<<dim3(128, 4, 3), 256, 0, stream>>>(
        query, key, value,
        wqh, wql, wkh, wkl, wvh, wvl,
        bq, bk, bvp,
        v, q_hi, q_lo, k_hi, k_lo);

    // per-(b,h) means (fused) + base output row
    means_fused<<<256, 256, 0, stream>>>(k_hi, k_lo, v, kmean, vmean);
    vmean_proj<<<128, 256, 0, stream>>>(vmean, Wo, bo, obase);

    // sparsity measure M (64 q-rows, Q aliased into Kp -> 33 KB LDS, 4 blk/CU)
    qk_rowmax_mfma<<<dim3(128, 16), 256, 0, stream>>>(q_hi, q_lo, k_hi, k_lo, kmean, Marr);
    topk35<<<128, 256, 0, stream>>>(Marr, idx);

    // reduced attention (K-split for parallelism)
    scores_red<<<dim3(128, 8), 256, 0, stream>>>(q_hi, q_lo, k_hi, k_lo, idx, mask, S);
    softmax_rows<<<B_ * H_ * U_, 256, 0, stream>>>(S);
    ctx_partial<<<dim3(128, 8), 256, 0, stream>>>(S, v, ctxp);   // ctxp aliases q_hi (dead)
    ctx_reduce_diff<<<1120, 256, 0, stream>>>(ctxp, vmean, ctxd);

    // output = broadcast base row + sparse delta (replaces full Wo GEMM)
    broadcast_out<<<8192, 256, 0, stream>>>(obase, out);
    delta_out<<<dim3(128, 4), 128, 0, stream>>>(ctxd, idx, Wo, out);
}

// Round 9
// 433.443 us; speedup vs baseline: 1.1800x; 1.0224x over previous
//
#include <hip/hip_runtime.h>
#include <math.h>

#define B_ 16
#define L_ 1024
#define H_ 8
#define U_ 35

typedef float f32x4 __attribute__((ext_vector_type(4)));
typedef short bf16x8 __attribute__((ext_vector_type(8)));

__device__ __forceinline__ unsigned short f2bf(float x) {
    unsigned int u = __float_as_uint(x);
    u += 0x7FFFu + ((u >> 16) & 1u);      // round-to-nearest-even
    return (unsigned short)(u >> 16);
}
__device__ __forceinline__ float bf2f(unsigned short b) {
    return __uint_as_float(((unsigned int)b) << 16);
}

// packed f32x2 -> bf16x2 in ONE VALU op (no builtin on gfx950; T12 recipe).
__device__ __forceinline__ unsigned int cvt_pk_bf16(float a, float b) {
    unsigned int r;
    asm("v_cvt_pk_bf16_f32 %0, %1, %2" : "=v"(r) : "v"(a), "v"(b));
    return r;
}

// async global->LDS, 16B per lane
__device__ __forceinline__ void gl_lds16(const void* g, void* l) {
    __builtin_amdgcn_global_load_lds(
        (const __attribute__((address_space(1))) unsigned int*)g,
        (__attribute__((address_space(3))) unsigned int*)l, 16, 0, 0);
}

#define MFMA(a, b, c) __builtin_amdgcn_mfma_f32_16x16x32_bf16((a), (b), (c), 0, 0, 0)

// ---------------- workspace layout (float-element offsets) ----------------
#define OFF_V      ((size_t)0)           // 8388608 f
#define OFF_QHI    ((size_t)8388608)     // 4194304
#define OFF_QLO    ((size_t)12582912)    // 4194304
#define OFF_CTXP   OFF_QHI               // ctx partials alias q_hi (dead after scores)
#define OFF_KHI    ((size_t)16777216)    // 4194304
#define OFF_KLO    ((size_t)20971520)    // 4194304
#define OFF_S      ((size_t)25165824)    // 4587520
#define OFF_WQH    OFF_S                 // W splits alias S (dead before scores)
#define OFF_WQL    ((size_t)(OFF_S + 131072))
#define OFF_WKH    ((size_t)(OFF_S + 262144))
#define OFF_WKL    ((size_t)(OFF_S + 393216))
#define OFF_WVH    ((size_t)(OFF_S + 524288))
#define OFF_WVL    ((size_t)(OFF_S + 655360))
#define OFF_M      ((size_t)29753344)    // 131072
#define OFF_STATS  OFF_M                 // softmax {m,inv} pairs alias Marr (dead after topk)
#define OFF_KMEAN  ((size_t)29884416)    // 8192
#define OFF_VMEAN  ((size_t)29892608)    // 8192
#define OFF_CTXD   ((size_t)29900800)    // 286720 (ctx - vmean diffs)
#define OFF_IDX    ((size_t)30187520)    // 4480
#define OFF_OBASE  ((size_t)30192000)    // 8192 (per-b base output row)
// end ~30.2M f = ~121 MB

// ---------------------------------------------------------------
// split Wq/Wk/Wv fp32 -> hi/lo bf16; grid 3072 x 256
// ---------------------------------------------------------------
__global__ __launch_bounds__(256) void split_w3(
    const float* __restrict__ Wq, const float* __restrict__ Wk,
    const float* __restrict__ Wv,
    unsigned short* __restrict__ wqh, unsigned short* __restrict__ wql,
    unsigned short* __restrict__ wkh, unsigned short* __restrict__ wkl,
    unsigned short* __restrict__ wvh, unsigned short* __restrict__ wvl)
{
    const int w = blockIdx.x >> 10;
    const int i = (blockIdx.x & 1023) * 256 + threadIdx.x;
    const float* W = (w == 0) ? Wq : (w == 1) ? Wk : Wv;
    unsigned short* hi = (w == 0) ? wqh : (w == 1) ? wkh : wvh;
    unsigned short* lo = (w == 0) ? wql : (w == 1) ? wkl : wvl;
    float x = W[i];
    unsigned short h = f2bf(x);
    hi[i] = h;
    lo[i] = f2bf(x - bf2f(h));
}

// ---------------------------------------------------------------
// Fused bf16x2 MFMA GEMM for all three projections (z = q/k/v).
// R5 config — best measured (123 us). Pinned lessons:
//  - B via global_load_lds (no VGPR roundtrip). R6's B reg-staging
//    SPILLED (WRITE 103->225 MB scratch, dur 124->195). Don't.
//  - A reg-prefetch (issue after barrier2, convert after barrier1) is
//    a win and fits the 96-VGPR budget.
//  - SQ_LDS_BANK_CONFLICT = 9437184 is INVARIANT to B-read swizzles
//    (R2/R4/R5) — not a B-read artifact; do not chase it.
// ---------------------------------------------------------------
__global__ __launch_bounds__(256) void gemm_qkv(
    const float* __restrict__ Aq, const float* __restrict__ Ak,
    const float* __restrict__ Av,
    const unsigned short* __restrict__ wqh, const unsigned short* __restrict__ wql,
    const unsigned short* __restrict__ wkh, const unsigned short* __restrict__ wkl,
    const unsigned short* __restrict__ wvh, const unsigned short* __restrict__ wvl,
    const float* __restrict__ bqp, const float* __restrict__ bkp,
    const float* __restrict__ bvp,
    float* __restrict__ vout,
    unsigned short* __restrict__ qhi_o, unsigned short* __restrict__ qlo_o,
    unsigned short* __restrict__ khi_o, unsigned short* __restrict__ klo_o)
{
    // one raw LDS pool, aliased: staging (36864 B) then epilogue Cf (34816 B)
    __shared__ __align__(16) unsigned char smem[36864];
    unsigned short (*Ah)[40] = (unsigned short (*)[40])(smem);            // 10240 B
    unsigned short (*Al)[40] = (unsigned short (*)[40])(smem + 10240);    // 10240 B
    unsigned char* Bh = smem + 20480;                                     //  8192 B [128][32] rot
    unsigned char* Bl = smem + 28672;                                     //  8192 B
    float (*Cf)[68] = (float (*)[68])(smem);                              // 34816 B

    const int z = blockIdx.z;
    const float* A = (z == 0) ? Aq : (z == 1) ? Ak : Av;
    const unsigned short* Whi = (z == 0) ? wqh : (z == 1) ? wkh : wvh;
    const unsigned short* Wlo = (z == 0) ? wql : (z == 1) ? wkl : wvl;
    const float* bias = (z == 0) ? bqp : (z == 1) ? bkp : bvp;
    unsigned short* ohi = (z == 0) ? qhi_o : (z == 1) ? khi_o : nullptr;
    unsigned short* olo = (z == 0) ? qlo_o : (z == 1) ? klo_o : nullptr;

    const int tid = threadIdx.x, lane = tid & 63, wave = tid >> 6;
    const int m0 = blockIdx.x * 128, n0 = blockIdx.y * 128;
    const int wm = (wave >> 1) * 64, wn = (wave & 1) * 64;

    f32x4 zero4 = {0.f, 0.f, 0.f, 0.f};
    f32x4 acc[4][4];
#pragma unroll
    for (int i = 0; i < 4; i++)
#pragma unroll
        for (int j = 0; j < 4; j++) acc[i][j] = zero4;

    const int ar = tid >> 3, ac = (tid & 7) * 4;
    const int kc = (lane >> 4) * 8;
    const int q4 = lane >> 4;
    const int fr = lane & 15;
    const int btr = tid >> 2;                                    // row in issue
    const int btc = ((((tid & 3) - btr - (btr >> 2)) & 3)) * 8;  // rotated src col
    const int bldsoff = tid * 16;                                // linear dest

    // T14: prologue A loads (tile 0)
    float4 areg[4];
#pragma unroll
    for (int p = 0; p < 4; ++p)
        areg[p] = *(const float4*)(A + (size_t)(m0 + ar + p * 32) * 512 + ac);

    for (int k0 = 0; k0 < 512; k0 += 32) {
        if (k0) __syncthreads();           // barrier1: prev readers done
        // --- B: async global->LDS (rotated source, linear dest)
#pragma unroll
        for (int i = 0; i < 2; ++i) {
            size_t gb = (size_t)(n0 + i * 64 + btr) * 512 + k0 + btc;
            gl_lds16(Whi + gb, Bh + i * 4096 + bldsoff);
            gl_lds16(Wlo + gb, Bl + i * 4096 + bldsoff);
        }
        // --- A: convert prefetched regs (no fresh load latency here)
#pragma unroll
        for (int p = 0; p < 4; ++p) {
            float4 a4 = areg[p];
            unsigned int h01 = cvt_pk_bf16(a4.x, a4.y);
            unsigned int h23 = cvt_pk_bf16(a4.z, a4.w);
            float r0 = a4.x - __uint_as_float(h01 << 16);
            float r1 = a4.y - __uint_as_float(h01 & 0xFFFF0000u);
            float r2 = a4.z - __uint_as_float(h23 << 16);
            float r3 = a4.w - __uint_as_float(h23 & 0xFFFF0000u);
            unsigned int l01 = cvt_pk_bf16(r0, r1);
            unsigned int l23 = cvt_pk_bf16(r2, r3);
            uint2 hh; hh.x = h01; hh.y = h23;
            uint2 ll; ll.x = l01; ll.y = l23;
            *(uint2*)&Ah[ar + p * 32][ac] = hh;
            *(uint2*)&Al[ar + p * 32][ac] = ll;
        }
        __syncthreads();   // barrier2: drains B vmcnt + A ds_writes
        // T14: issue NEXT tile's A loads — fly under the MFMA phase.
        if (k0 + 32 < 512) {
#pragma unroll
            for (int p = 0; p < 4; ++p)
                areg[p] = *(const float4*)(A + (size_t)(m0 + ar + p * 32) * 512 + k0 + 32 + ac);
        }

        bf16x8 ah[4], al[4];
#pragma unroll
        for (int mi = 0; mi < 4; ++mi) {
            int row = wm + mi * 16 + fr;
            ah[mi] = *(bf16x8*)&Ah[row][kc];
            al[mi] = *(bf16x8*)&Al[row][kc];
        }
#pragma unroll
        for (int ni = 0; ni < 4; ++ni) {
            int rn = wn + ni * 16 + fr;
            int sl = (q4 + rn + (rn >> 2)) & 3;          // rotated read slot
            int bb = rn * 64 + sl * 16;
            bf16x8 bh8 = *(bf16x8*)(Bh + bb);
            bf16x8 bl8 = *(bf16x8*)(Bl + bb);
#pragma unroll
            for (int mi = 0; mi < 4; ++mi) {
                acc[mi][ni] = MFMA(ah[mi], bh8, acc[mi][ni]);
                acc[mi][ni] = MFMA(ah[mi], bl8, acc[mi][ni]);
                acc[mi][ni] = MFMA(al[mi], bh8, acc[mi][ni]);
            }
        }
    }

    // ---------------- epilogue: LDS-staged, coalesced stores ----------------
    const int col = lane & 15, rq = (lane >> 4) * 4;
    const int b_ = m0 >> 10;       // 128-row tile lies within one b
    const int l0 = m0 & 1023;

#pragma unroll
    for (int half = 0; half < 2; ++half) {
        __syncthreads();           // staging buffers dead / previous half stored
        if ((wave & 1) == half) {  // waves holding cols [half*64, half*64+64)
#pragma unroll
            for (int ni = 0; ni < 4; ++ni) {
                float bn = bias[n0 + half * 64 + ni * 16 + col];
#pragma unroll
                for (int mi = 0; mi < 4; ++mi)
#pragma unroll
                    for (int r = 0; r < 4; ++r)
                        Cf[wm + mi * 16 + rq + r][ni * 16 + col] = acc[mi][ni][r] + bn;
            }
        }
        __syncthreads();
        const int h_ = (n0 >> 6) + half;
        const size_t plane = ((size_t)(b_ * H_ + h_) * L_ + l0) * 64;
        if (z == 2) {
            const int r = tid >> 1, d0 = (tid & 1) * 32;
#pragma unroll
            for (int j = 0; j < 8; ++j) {
                float4 val = *(const float4*)&Cf[r][d0 + j * 4];
                *(float4*)(vout + plane + (size_t)r * 64 + d0 + j * 4) = val;
            }
        } else {
            const int r = tid >> 1, d0 = (tid & 1) * 32;
#pragma unroll
            for (int c = 0; c < 4; ++c) {
                float x[8];
#pragma unroll
                for (int j = 0; j < 8; ++j) x[j] = Cf[r][d0 + c * 8 + j];
                unsigned int h01 = cvt_pk_bf16(x[0], x[1]);
                unsigned int h23 = cvt_pk_bf16(x[2], x[3]);
                unsigned int h45 = cvt_pk_bf16(x[4], x[5]);
                unsigned int h67 = cvt_pk_bf16(x[6], x[7]);
                float r0 = x[0] - __uint_as_float(h01 << 16);
                float r1 = x[1] - __uint_as_float(h01 & 0xFFFF0000u);
                float r2 = x[2] - __uint_as_float(h23 << 16);
                float r3 = x[3] - __uint_as_float(h23 & 0xFFFF0000u);
                float r4 = x[4] - __uint_as_float(h45 << 16);
                float r5 = x[5] - __uint_as_float(h45 & 0xFFFF0000u);
                float r6 = x[6] - __uint_as_float(h67 << 16);
                float r7 = x[7] - __uint_as_float(h67 & 0xFFFF0000u);
                uint4 ph; ph.x = h01; ph.y = h23; ph.z = h45; ph.w = h67;
                uint4 pl;
                pl.x = cvt_pk_bf16(r0, r1);
                pl.y = cvt_pk_bf16(r2, r3);
                pl.z = cvt_pk_bf16(r4, r5);
                pl.w = cvt_pk_bf16(r6, r7);
                *(uint4*)(ohi + plane + (size_t)r * 64 + d0 + c * 8) = ph;
                *(uint4*)(olo + plane + (size_t)r * 64 + d0 + c * 8) = pl;
            }
        }
    }
}

// ---------------------------------------------------------------
// fused means: blocks 0..127 -> kmean (from k hi/lo), 128..255 -> vmean (fp32)
// ---------------------------------------------------------------
__global__ __launch_bounds__(256) void means_fused(
    const unsigned short* __restrict__ khi, const unsigned short* __restrict__ klo,
    const float* __restrict__ v, float* __restrict__ kmean, float* __restrict__ vmean)
{
    const int which = blockIdx.x >> 7;
    const int bh = blockIdx.x & 127;
    const int d = threadIdx.x & 63, g = threadIdx.x >> 6;
    __shared__ float red[4][64];
    float s = 0.f;
    if (which == 0) {
        size_t base = ((size_t)bh * L_ + g * 256) * 64 + d;
#pragma unroll 8
        for (int l = 0; l < 256; l++) {
            size_t o = base + (size_t)l * 64;
            s += bf2f(khi[o]) + bf2f(klo[o]);
        }
    } else {
        const float* p = v + ((size_t)bh * L_ + g * 256) * 64 + d;
#pragma unroll 8
        for (int l = 0; l < 256; l++) s += p[(size_t)l * 64];
    }
    red[g][d] = s;
    __syncthreads();
    if (threadIdx.x < 64) {
        const int dd = threadIdx.x;
        float m = (red[0][dd] + red[1][dd] + red[2][dd] + red[3][dd]) * (1.0f / 1024.0f);
        (which == 0 ? kmean : vmean)[(size_t)bh * 64 + dd] = m;
    }
}

// ---------------------------------------------------------------
// M[l] = max_k(q_l . k_k) - q_l . kmean via bf16x2 MFMA
// grid (128 bh, 16 qt) — R4 version EXACT (best measured).
// R8's Q-aliased variant regressed +14 us (serialized prologue:
// Q-latency, barrier, hoist, barrier, K0-latency all exposed).
// Here Q and K0 loads overlap before one barrier.
// ---------------------------------------------------------------
__global__ __launch_bounds__(256) void qk_rowmax_mfma(
    const unsigned short* __restrict__ qhi, const unsigned short* __restrict__ qlo,
    const unsigned short* __restrict__ khi, const unsigned short* __restrict__ klo,
    const float* __restrict__ kmean, float* __restrict__ Mout)
{
    __shared__ unsigned short Qh[64][72], Ql[64][72];      // 18432 B
    __shared__ __align__(16) unsigned char Kp[2][2][8192]; // [buf][hi/lo], swz
    __shared__ float Mred[64][4];
    __shared__ float km[64];
    const int bh = blockIdx.x, q0 = blockIdx.y * 64;
    const int tid = threadIdx.x, lane = tid & 63, wave = tid >> 6;

    if (tid < 64) km[tid] = kmean[bh * 64 + tid];
    {
        int r = tid >> 2, c = (tid & 3) * 16;
        size_t off = ((size_t)bh * L_ + q0 + r) * 64 + c;
        *(uint4*)&Qh[r][c]     = *(const uint4*)(qhi + off);
        *(uint4*)&Qh[r][c + 8] = *(const uint4*)(qhi + off + 8);
        *(uint4*)&Ql[r][c]     = *(const uint4*)(qlo + off);
        *(uint4*)&Ql[r][c + 8] = *(const uint4*)(qlo + off + 8);
    }

    const size_t kb = (size_t)bh * L_ * 64;
    const int srow = tid >> 3;
    const int scol = ((tid & 7) ^ ((tid >> 3) & 7)) * 8;
    const int sdst = tid * 16;

    // stage K tile 0 into buf 0 (overlaps the Q uint4 loads above)
    {
        size_t g0 = kb + (size_t)(srow) * 64 + scol;
        size_t g1 = kb + (size_t)(32 + srow) * 64 + scol;
        gl_lds16(khi + g0, &Kp[0][0][sdst]);
        gl_lds16(khi + g1, &Kp[0][0][4096 + sdst]);
        gl_lds16(klo + g0, &Kp[0][1][sdst]);
        gl_lds16(klo + g1, &Kp[0][1][4096 + sdst]);
    }
    __syncthreads();   // Q/km staged + K tile 0 complete (vmcnt+lgkm drain)

    const int fr = lane & 15;
    f32x4 zero4 = {0.f, 0.f, 0.f, 0.f};

    // hoist Q fragments into registers — invariant across the K loop
    bf16x8 qah[2][4], qal[2][4];
#pragma unroll
    for (int ks = 0; ks < 2; ++ks) {
        int kcol = ks * 32 + (lane >> 4) * 8;
#pragma unroll
        for (int mi = 0; mi < 4; ++mi) {
            qah[ks][mi] = *(bf16x8*)&Qh[mi * 16 + fr][kcol];
            qal[ks][mi] = *(bf16x8*)&Ql[mi * 16 + fr][kcol];
        }
    }

    float rmax[4][4];
#pragma unroll
    for (int mi = 0; mi < 4; ++mi)
#pragma unroll
        for (int r = 0; r < 4; ++r) rmax[mi][r] = -INFINITY;

    const int krow = wave * 16 + fr;
    const int kbase = krow * 128;
    const int kxor = (krow & 7) << 4;

    for (int kt = 0; kt < 16; ++kt) {
        const int cur = kt & 1;
        if (kt < 15) {   // stage next tile into the other buffer (async)
            const int nb = cur ^ 1;
            size_t g0 = kb + (size_t)((kt + 1) * 64 + srow) * 64 + scol;
            size_t g1 = g0 + (size_t)32 * 64;
            gl_lds16(khi + g0, &Kp[nb][0][sdst]);
            gl_lds16(khi + g1, &Kp[nb][0][4096 + sdst]);
            gl_lds16(klo + g0, &Kp[nb][1][sdst]);
            gl_lds16(klo + g1, &Kp[nb][1][4096 + sdst]);
        }

        f32x4 acc[4];
#pragma unroll
        for (int mi = 0; mi < 4; ++mi) acc[mi] = zero4;

#pragma unroll
        for (int ks = 0; ks < 2; ++ks) {
            int byte = kbase + (((ks * 32 + (lane >> 4) * 8) * 2) ^ kxor);
            bf16x8 bh8 = *(bf16x8*)&Kp[cur][0][byte];
            bf16x8 bl8 = *(bf16x8*)&Kp[cur][1][byte];
#pragma unroll
            for (int mi = 0; mi < 4; ++mi) {
                acc[mi] = MFMA(qah[ks][mi], bh8, acc[mi]);
                acc[mi] = MFMA(qah[ks][mi], bl8, acc[mi]);
                acc[mi] = MFMA(qal[ks][mi], bh8, acc[mi]);
            }
        }
#pragma unroll
        for (int mi = 0; mi < 4; ++mi)
#pragma unroll
            for (int r = 0; r < 4; ++r)
                rmax[mi][r] = fmaxf(rmax[mi][r], acc[mi][r]);

        __syncthreads();   // next-tile loads drained; buffers synced
    }

    // reduce over the 16 k-columns held across lanes of each 16-group
#pragma unroll
    for (int mi = 0; mi < 4; ++mi)
#pragma unroll
        for (int r = 0; r < 4; ++r) {
            float v = rmax[mi][r];
            v = fmaxf(v, __shfl_xor(v, 1));
            v = fmaxf(v, __shfl_xor(v, 2));
            v = fmaxf(v, __shfl_xor(v, 4));
            v = fmaxf(v, __shfl_xor(v, 8));
            rmax[mi][r] = v;
        }
    if ((lane & 15) == 0) {
        int quad = lane >> 4;
#pragma unroll
        for (int mi = 0; mi < 4; ++mi)
#pragma unroll
            for (int r = 0; r < 4; ++r)
                Mred[mi * 16 + quad * 4 + r][wave] = rmax[mi][r];
    }
    __syncthreads();
    if (tid < 64) {
        float mx = fmaxf(fmaxf(Mred[tid][0], Mred[tid][1]),
                         fmaxf(Mred[tid][2], Mred[tid][3]));
        float dot = 0.f;
#pragma unroll 4
        for (int d = 0; d < 64; ++d)
            dot = fmaf(bf2f(Qh[tid][d]) + bf2f(Ql[tid][d]), km[d], dot);
        Mout[(size_t)bh * L_ + q0 + tid] = mx - dot;
    }
}

// ---------------------------------------------------------------
// top-35 of M[1024] per (b,h) — iterative version (measured-good).
// R7's radix-select REGRESSED +61 us (clustered keys serialize the
// LDS atomic histogram; tid0 equals-scan is 1024 serial LDS reads).
// ---------------------------------------------------------------
__global__ __launch_bounds__(256) void topk35(
    const float* __restrict__ Min, int* __restrict__ idx_out)
{
    const int bh = blockIdx.x;
    const int tid = threadIdx.x;
    __shared__ float vals[1024];
    __shared__ float wv[4];
    __shared__ int wi[4];
    for (int i = tid; i < 1024; i += 256) vals[i] = Min[(size_t)bh * 1024 + i];
    __syncthreads();
    for (int it = 0; it < U_; ++it) {
        float bv = -INFINITY; int bi = 1 << 30;
        for (int i = tid; i < 1024; i += 256) {
            float x = vals[i];
            if (x > bv) { bv = x; bi = i; }
        }
#pragma unroll
        for (int off = 32; off; off >>= 1) {
            float ov = __shfl_down(bv, off);
            int   oi = __shfl_down(bi, off);
            if (ov > bv || (ov == bv && oi < bi)) { bv = ov; bi = oi; }
        }
        if ((tid & 63) == 0) { wv[tid >> 6] = bv; wi[tid >> 6] = bi; }
        __syncthreads();
        if (tid == 0) {
#pragma unroll
            for (int w = 1; w < 4; ++w) {
                if (wv[w] > bv || (wv[w] == bv && wi[w] < bi)) { bv = wv[w]; bi = wi[w]; }
            }
            idx_out[bh * U_ + it] = bi;
            vals[bi] = -INFINITY;
        }
        __syncthreads();
    }
}

// ---------------------------------------------------------------
// S[u][k] = (q[idx_u] . k_k)/8 masked; grid (128 bh, 8 key-chunks)
// ---------------------------------------------------------------
__global__ __launch_bounds__(256) void scores_red(
    const unsigned short* __restrict__ qhi, const unsigned short* __restrict__ qlo,
    const unsigned short* __restrict__ khi, const unsigned short* __restrict__ klo,
    const int* __restrict__ idx, const int* __restrict__ mask,
    float* __restrict__ S)
{
    __shared__ float Qs[64][36];
    __shared__ float Ks[64][68];
    const int bh = blockIdx.x;
    const int b = bh >> 3;
    const int tid = threadIdx.x;
    const int tk = tid & 63, tg = tid >> 6;

    for (int t = tid; t < 36 * 64; t += 256) {
        int u = t >> 6, d = t & 63;
        float val = 0.f;
        if (u < U_) {
            int l = idx[bh * U_ + u];
            size_t off = ((size_t)bh * L_ + l) * 64 + d;
            val = bf2f(qhi[off]) + bf2f(qlo[off]);
        }
        Qs[d][u] = val;
    }

    const size_t kb = (size_t)bh * L_ * 64;
    const int sr = tid >> 2, sc = (tid & 3) * 16;
    float acc[9];
    const int kt0 = blockIdx.y * 2;
    for (int ki = 0; ki < 2; ++ki) {
        int kt = kt0 + ki;
        if (ki) __syncthreads();
        {
            size_t off = kb + (size_t)(kt * 64 + sr) * 64 + sc;
            uint4 h0 = *(const uint4*)(khi + off);
            uint4 h1 = *(const uint4*)(khi + off + 8);
            uint4 l0 = *(const uint4*)(klo + off);
            uint4 l1 = *(const uint4*)(klo + off + 8);
            unsigned short hv[16], lv[16];
            *(uint4*)hv = h0; *(uint4*)(hv + 8) = h1;
            *(uint4*)lv = l0; *(uint4*)(lv + 8) = l1;
#pragma unroll
            for (int i = 0; i < 16; ++i)
                Ks[sc + i][sr] = bf2f(hv[i]) + bf2f(lv[i]);
        }
        __syncthreads();
#pragma unroll
        for (int j = 0; j < 9; j++) acc[j] = 0.f;
#pragma unroll 4
        for (int d = 0; d < 64; ++d) {
            float kv = Ks[d][tk];
#pragma unroll
            for (int j = 0; j < 9; j++) acc[j] = fmaf(Qs[d][tg + 4 * j], kv, acc[j]);
        }
        const int kcol = kt * 64 + tk;
        const bool msk = (mask[b * L_ + kcol] == 0);
#pragma unroll
        for (int j = 0; j < 9; j++) {
            int u = tg + 4 * j;
            if (u < U_)
                S[((size_t)bh * U_ + u) * 1024 + kcol] = msk ? -INFINITY : acc[j] * 0.125f;
        }
    }
}

// ---------------------------------------------------------------
// softmax row stats: {m, 1/sum} per row; grid 4480 rows.
// R9: replaces the in-place softmax_rows (18MB read + 18MB write).
// Same reduction structure -> identical m and sum; ctx_partial
// applies exp(x-m)*inv on load -> attn values bit-identical.
// ---------------------------------------------------------------
__global__ __launch_bounds__(256) void softmax_stats(
    const float* __restrict__ S, float* __restrict__ stats)
{
    const size_t base = (size_t)blockIdx.x * 1024;
    const int tid = threadIdx.x;
    __shared__ float redm[4];
    __shared__ float reds[4];
    float4 v = *(const float4*)(S + base + tid * 4);
    float mx = fmaxf(fmaxf(v.x, v.y), fmaxf(v.z, v.w));
#pragma unroll
    for (int off = 32; off; off >>= 1) mx = fmaxf(mx, __shfl_down(mx, off));
    if ((tid & 63) == 0) redm[tid >> 6] = mx;
    __syncthreads();
    mx = fmaxf(fmaxf(redm[0], redm[1]), fmaxf(redm[2], redm[3]));
    float e0 = __expf(v.x - mx), e1 = __expf(v.y - mx);
    float e2 = __expf(v.z - mx), e3 = __expf(v.w - mx);
    float s = e0 + e1 + e2 + e3;
#pragma unroll
    for (int off = 32; off; off >>= 1) s += __shfl_down(s, off);
    if ((tid & 63) == 0) reds[tid >> 6] = s;
    __syncthreads();
    if (tid == 0) {
        s = reds[0] + reds[1] + reds[2] + reds[3];
        stats[(size_t)blockIdx.x * 2]     = mx;
        stats[(size_t)blockIdx.x * 2 + 1] = 1.0f / s;
    }
}

// ---------------------------------------------------------------
// ctx partials: grid (128 bh, 8 kc). Applies softmax on load:
// Wt = exp(Sraw - m) * inv  (bit-identical to pre-softmaxed S).
// ---------------------------------------------------------------
__global__ __launch_bounds__(256) void ctx_partial(
    const float* __restrict__ S, const float* __restrict__ stats,
    const float* __restrict__ v, float* __restrict__ ctxp)
{
    __shared__ float Vs[128][68];
    __shared__ float Wt[36][128];
    const int bh = blockIdx.x, kc = blockIdx.y;
    const int tid = threadIdx.x;
    const int td = tid & 63, tg = tid >> 6;
    const int lr = tid >> 2, lc0 = (tid & 3) * 16;

    const float* vbase = v + ((size_t)bh * L_ + kc * 128) * 64;
    const float* Sbase = S + (size_t)bh * U_ * 1024 + kc * 128;

#pragma unroll
    for (int hh = 0; hh < 2; ++hh) {
        int row = lr + hh * 64;
        const float* src = vbase + (size_t)row * 64 + lc0;
        *(float4*)&Vs[row][lc0 + 0]  = *(const float4*)(src + 0);
        *(float4*)&Vs[row][lc0 + 4]  = *(const float4*)(src + 4);
        *(float4*)&Vs[row][lc0 + 8]  = *(const float4*)(src + 8);
        *(float4*)&Vs[row][lc0 + 12] = *(const float4*)(src + 12);
    }
    for (int t = tid; t < 36 * 128; t += 256) {
        int u = t >> 7, kk = t & 127;
        float w = 0.f;
        if (u < U_) {
            float m   = stats[((size_t)bh * U_ + u) * 2];
            float inv = stats[((size_t)bh * U_ + u) * 2 + 1];
            w = __expf(Sbase[(size_t)u * 1024 + kk] - m) * inv;
        }
        Wt[u][kk] = w;
    }
    __syncthreads();

    float acc[9];
#pragma unroll
    for (int j = 0; j < 9; j++) acc[j] = 0.f;
#pragma unroll 2
    for (int kk = 0; kk < 128; ++kk) {
        float vv = Vs[kk][td];
#pragma unroll
        for (int j = 0; j < 9; j++) acc[j] = fmaf(Wt[tg + 4 * j][kk], vv, acc[j]);
    }
#pragma unroll
    for (int j = 0; j < 9; j++) {
        int u = tg + 4 * j;
        if (u < U_)
            ctxp[((size_t)(kc * 128 + bh) * 36 + u) * 64 + td] = acc[j];
    }
}

// ---------------------------------------------------------------
// ctxd[bh][u][d] = sum_kc ctxp - vmean[bh][d] ; grid 1120 x 256
// ---------------------------------------------------------------
__global__ __launch_bounds__(256) void ctx_reduce_diff(
    const float* __restrict__ ctxp, const float* __restrict__ vmean,
    float* __restrict__ ctxd)
{
    const int i = blockIdx.x * 256 + threadIdx.x;   // 128*35*64 = 286720
    const int d = i & 63;
    const int rest = i >> 6;
    const int u = rest % U_;
    const int bh = rest / U_;
    float s = 0.f;
#pragma unroll
    for (int kc = 0; kc < 8; ++kc)
        s += ctxp[((size_t)(kc * 128 + bh) * 36 + u) * 64 + d];
    ctxd[i] = s - vmean[(size_t)bh * 64 + d];
}

// ---------------------------------------------------------------
// obase[b][n] = dot(xbar[b], Wo[n]) + bo[n] ; grid 128 (16 b x 8 nchunk)
// ---------------------------------------------------------------
__global__ __launch_bounds__(256) void vmean_proj(
    const float* __restrict__ vmean, const float* __restrict__ Wo,
    const float* __restrict__ bo, float* __restrict__ obase)
{
    const int b = blockIdx.x >> 3, n0 = (blockIdx.x & 7) * 64;
    const int tid = threadIdx.x;
    __shared__ float xbar[512];
    __shared__ float psum[64][5];
    for (int i = tid; i < 512; i += 256)
        xbar[i] = vmean[(size_t)(b * 8 + (i >> 6)) * 64 + (i & 63)];
    __syncthreads();
    const int n = n0 + (tid >> 2), fq = (tid & 3) * 128;
    float s = 0.f;
    for (int f = 0; f < 128; f += 4) {
        float4 w = *(const float4*)(Wo + (size_t)n * 512 + fq + f);
        s += xbar[fq + f] * w.x + xbar[fq + f + 1] * w.y +
             xbar[fq + f + 2] * w.z + xbar[fq + f + 3] * w.w;
    }
    psum[tid >> 2][tid & 3] = s;
    __syncthreads();
    if (tid < 64)
        obase[(size_t)b * 512 + n0 + tid] =
            psum[tid][0] + psum[tid][1] + psum[tid][2] + psum[tid][3] + bo[n0 + tid];
}

// ---------------------------------------------------------------
// out[b][l][:] = obase[b][:] ; grid 8192 x 256 (float4)
// ---------------------------------------------------------------
__global__ void broadcast_out(const float* __restrict__ obase, float* __restrict__ out)
{
    const size_t e = ((size_t)blockIdx.x * 256 + threadIdx.x) * 4;
    const int n = (int)(e & 511);
    const int b = (int)(e >> 19);
    *(float4*)(out + e) = *(const float4*)(obase + (b << 9) + n);
}

// ---------------------------------------------------------------
// out[b][l_u][n] += ctxd[bh][u] . Wo[n][h*64..]
// grid (128 bh, 4 col-chunks) x 128 threads; one column n per thread.
// ---------------------------------------------------------------
__global__ __launch_bounds__(128) void delta_out(
    const float* __restrict__ ctxd, const int* __restrict__ idx,
    const float* __restrict__ Wo, float* __restrict__ out)
{
    const int bh = blockIdx.x, b = bh >> 3, h = bh & 7;
    const int tid = threadIdx.x;
    const int n = blockIdx.y * 128 + tid;
    __shared__ float sd[U_][64];
    __shared__ int ls[U_];
    if (tid < U_) ls[tid] = idx[bh * U_ + tid];
    for (int t = tid; t < U_ * 64; t += 128)
        sd[t >> 6][t & 63] = ctxd[(size_t)bh * U_ * 64 + t];

    float4 w[16];
    const float* wp = Wo + (size_t)n * 512 + h * 64;
#pragma unroll
    for (int jc = 0; jc < 16; ++jc) w[jc] = *(const float4*)(wp + jc * 4);
    __syncthreads();

    for (int u = 0; u < U_; ++u) {
        float acc = 0.f;
#pragma unroll
        for (int jc = 0; jc < 16; ++jc) {
            float4 dv = *(const float4*)&sd[u][jc * 4];
            acc = fmaf(dv.w, w[jc].w, fmaf(dv.z, w[jc].z,
                  fmaf(dv.y, w[jc].y, fmaf(dv.x, w[jc].x, acc))));
        }
        atomicAdd(out + ((size_t)b * L_ + ls[u]) * 512 + n, acc);
    }
}

// ---------------------------------------------------------------
extern "C" void kernel_launch(void* const* d_in, const int* in_sizes, int n_in,
                              void* d_out, int out_size, void* d_ws, size_t ws_size,
                              hipStream_t stream)
{
    (void)in_sizes; (void)n_in; (void)out_size; (void)ws_size;
    const float* query = (const float*)d_in[0];
    const float* key   = (const float*)d_in[1];
    const float* value = (const float*)d_in[2];
    const int*   mask  = (const int*)d_in[3];
    const float* Wq = (const float*)d_in[4];
    const float* bq = (const float*)d_in[5];
    const float* Wk = (const float*)d_in[6];
    const float* bk = (const float*)d_in[7];
    const float* Wv = (const float*)d_in[8];
    const float* bvp = (const float*)d_in[9];
    const float* Wo = (const float*)d_in[10];
    const float* bo = (const float*)d_in[11];
    float* out = (float*)d_out;

    float* ws = (float*)d_ws;
    float* v      = ws + OFF_V;
    unsigned short* q_hi = (unsigned short*)(ws + OFF_QHI);
    unsigned short* q_lo = (unsigned short*)(ws + OFF_QLO);
    unsigned short* k_hi = (unsigned short*)(ws + OFF_KHI);
    unsigned short* k_lo = (unsigned short*)(ws + OFF_KLO);
    float* ctxp   = ws + OFF_CTXP;
    float* S      = ws + OFF_S;
    float* Marr   = ws + OFF_M;
    float* stats  = ws + OFF_STATS;   // aliases Marr (dead after topk35)
    float* kmean  = ws + OFF_KMEAN;
    float* vmean  = ws + OFF_VMEAN;
    float* ctxd   = ws + OFF_CTXD;
    int*   idx    = (int*)(ws + OFF_IDX);
    float* obase  = ws + OFF_OBASE;
    unsigned short* wqh = (unsigned short*)(ws + OFF_WQH);
    unsigned short* wql = (unsigned short*)(ws + OFF_WQL);
    unsigned short* wkh = (unsigned short*)(ws + OFF_WKH);
    unsigned short* wkl = (unsigned short*)(ws + OFF_WKL);
    unsigned short* wvh = (unsigned short*)(ws + OFF_WVH);
    unsigned short* wvl = (unsigned short*)(ws + OFF_WVL);

    // weight splits (fused)
    split_w3<<<3072, 256, 0, stream>>>(Wq, Wk, Wv, wqh, wql, wkh, wkl, wvh, wvl);

    // projections: R5 config (gload_lds B + A reg-prefetch) — best measured.
    gemm_qkv<<<dim3(128, 4, 3), 256, 0, stream>>>(
        query, key, value,
        wqh, wql, wkh, wkl, wvh, wvl,
        bq, bk, bvp,
        v, q_hi, q_lo, k_hi, k_lo);

    // per-(b,h) means (fused) + base output row
    means_fused<<<256, 256, 0, stream>>>(k_hi, k_lo, v, kmean, vmean);
    vmean_proj<<<128, 256, 0, stream>>>(vmean, Wo, bo, obase);

    // sparsity measure M (R4 config — best measured) + top-35
    qk_rowmax_mfma<<<dim3(128, 16), 256, 0, stream>>>(q_hi, q_lo, k_hi, k_lo, kmean, Marr);
    topk35<<<128, 256, 0, stream>>>(Marr, idx);

    // reduced attention: scores -> row stats -> ctx (softmax applied on load)
    scores_red<<<dim3(128, 8), 256, 0, stream>>>(q_hi, q_lo, k_hi, k_lo, idx, mask, S);
    softmax_stats<<<B_ * H_ * U_, 256, 0, stream>>>(S, stats);
    ctx_partial<<<dim3(128, 8), 256, 0, stream>>>(S, stats, v, ctxp);  // ctxp aliases q_hi
    ctx_reduce_diff<<<1120, 256, 0, stream>>>(ctxp, vmean, ctxd);

    // output = broadcast base row + sparse delta (replaces full Wo GEMM)
    broadcast_out<<<8192, 256, 0, stream>>>(obase, out);
    delta_out<<<dim3(128, 4), 128, 0, stream>>>(ctxd, idx, Wo, out);
}